// Round 1
// baseline (387.459 us; speedup 1.0000x reference)
//
#include <hip/hip_runtime.h>
#include <math.h>

#define NN 64      // nodes
#define NF 64      // input features
#define NE 128     // embed
#define NH 256     // hidden
#define NA 6       // atoms
#define NB 4096    // batch
#define NT (NB*NN) // tokens = 262144

// ---- workspace layout (float offsets) ----
#define OFF_ADJ   0u                       // 64*64
#define OFF_WMIX  4096u                    // 64*64*128
#define OFF_BMIX  528384u                  // 64*128
#define OFF_WE2   536576u                  // 64*64*256   (16B aligned)
#define OFF_BE2   1585152u                 // 64*256
#define OFF_WATTN 1601536u                 // 256*6  [j][a]
#define OFF_BATTN 1603072u                 // 6
#define OFF_S     1603078u                 // 64 partial sums (per n)
#define OFF_C     1603142u                 // 1
#define OFF_XT    1603144u                 // 64*4096 transposed x (16B aligned)
#define OFF_ARAW  1865288u                 // 2*NT*6
// total 5011016 floats ~= 19.2 MB

// ---------------------------------------------------------------- P1:
// adj (sigmoid*mask, row-normalized), K=basis@Wk, WqK, Wattn, battn, zero S
__global__ void kP1(const float* __restrict__ adjw, const float* __restrict__ basis,
                    const float* __restrict__ Wq, const float* __restrict__ Wk,
                    const float* __restrict__ W2, const float* __restrict__ b2,
                    float* __restrict__ ws) {
    __shared__ float Ks[NA * NE];    // K[a][e2]
    __shared__ float WqK[NE * NA];   // [e][a]
    const int t = threadIdx.x;

    if (t < NN) {
        int r = t >> 3, c = t & 7;
        float sum = 0.f;
        for (int m = 0; m < NN; ++m) {
            int mr = m >> 3, mc = m & 7;
            int man = abs(mr - r) + abs(mc - c);
            float v = 0.f;
            if (man == 1) v = 1.f / (1.f + expf(-adjw[t * NN + m]));
            ws[OFF_ADJ + t * NN + m] = v;
            sum += v;
        }
        float inv = 1.f / fmaxf(sum, 1e-6f);
        for (int m = 0; m < NN; ++m) ws[OFF_ADJ + t * NN + m] *= inv;
    }
    // K[a][e2] = sum_e basis[a,e]*Wk[e,e2]
    for (int q = t; q < NA * NE; q += 256) {
        int a = q >> 7, e2 = q & 127;
        float acc = 0.f;
        for (int e = 0; e < NE; ++e) acc = fmaf(basis[a * NE + e], Wk[e * NE + e2], acc);
        Ks[a * NE + e2] = acc;
    }
    __syncthreads();
    // WqK[e][a] = sum_e2 Wq[e,e2]*K[a,e2]
    for (int q = t; q < NE * NA; q += 256) {
        int e = q / NA, a = q - e * NA;
        float acc = 0.f;
        for (int e2 = 0; e2 < NE; ++e2) acc = fmaf(Wq[e * NE + e2], Ks[a * NE + e2], acc);
        WqK[e * NA + a] = acc;
    }
    __syncthreads();
    const float scale = 1.f / (sqrtf(128.f) + 1e-8f);
    {   // Wattn[j][a] = scale * sum_e W2[j,e]*WqK[e][a]
        int j = t;  // 256 threads = 256 rows
        for (int a = 0; a < NA; ++a) {
            float acc = 0.f;
            for (int e = 0; e < NE; ++e) acc = fmaf(W2[j * NE + e], WqK[e * NA + a], acc);
            ws[OFF_WATTN + j * NA + a] = acc * scale;
        }
    }
    if (t < NA) {
        float acc = 0.f;
        for (int e = 0; e < NE; ++e) acc = fmaf(b2[e], WqK[e * NA + t], acc);
        ws[OFF_BATTN + t] = acc * scale;
    }
    if (t < 64) ws[OFF_S + t] = 0.f;
}

// ---------------------------------------------------------------- P2:
// Wmix[n][f][e] = sum_m adj[n,m]*W_embed[f, m*128+e] ; bmix[n][e] likewise
__global__ void kP2(const float* __restrict__ Wemb, const float* __restrict__ bemb,
                    float* __restrict__ ws) {
    __shared__ float adjs[NN];
    const int n = blockIdx.x, t = threadIdx.x;
    if (t < NN) adjs[t] = ws[OFF_ADJ + n * NN + t];
    __syncthreads();
    for (int i = 0; i < 32; ++i) {
        int q = i * 256 + t;                 // 0..8191
        int f = q >> 7, e = q & 127;
        float acc = 0.f;
        for (int m = 0; m < NN; ++m) {
            float a = adjs[m];
            if (a != 0.f) acc = fmaf(a, Wemb[(size_t)f * (NN * NE) + m * NE + e], acc);
        }
        ws[OFF_WMIX + ((size_t)n * NF + f) * NE + e] = acc;
    }
    if (t < NE) {
        float acc = 0.f;
        for (int m = 0; m < NN; ++m) {
            float a = adjs[m];
            if (a != 0.f) acc = fmaf(a, bemb[m * NE + t], acc);
        }
        ws[OFF_BMIX + n * NE + t] = acc;
    }
}

// ---------------------------------------------------------------- P3:
// We2[n][f][j] = sum_e Wmix[n][f][e]*W1[e][j]; be2[n][j] = bmix@W1 + b1
__global__ void kP3(const float* __restrict__ W1, const float* __restrict__ b1,
                    float* __restrict__ ws) {
    __shared__ float rows[4 * NE];
    __shared__ float brow[NE];
    const int n = blockIdx.x, fb = blockIdx.y * 4, t = threadIdx.x;
    for (int i = 0; i < 2; ++i) {
        int q = i * 256 + t;
        rows[q] = ws[OFF_WMIX + ((size_t)n * NF + fb) * NE + q];
    }
    const bool doB = (blockIdx.y == 0);
    if (doB && t < NE) brow[t] = ws[OFF_BMIX + n * NE + t];
    __syncthreads();
    float acc[4] = {0.f, 0.f, 0.f, 0.f};
    float accb = 0.f;
    for (int e = 0; e < NE; ++e) {
        float w = W1[e * NH + t];
        #pragma unroll
        for (int f = 0; f < 4; ++f) acc[f] = fmaf(rows[f * NE + e], w, acc[f]);
        if (doB) accb = fmaf(brow[e], w, accb);
    }
    #pragma unroll
    for (int f = 0; f < 4; ++f)
        ws[OFF_WE2 + ((size_t)n * NF + fb + f) * NH + t] = acc[f];
    if (doB) ws[OFF_BE2 + n * NH + t] = accb + b1[t];
}

// ---------------------------------------------------------------- P4:
// transpose x [4096][64] -> Xt [64][4096]
__global__ void kP4(const float* __restrict__ x, float* __restrict__ ws) {
    __shared__ float T[64][65];
    const int bt = blockIdx.x, t = threadIdx.x;
    for (int i = 0; i < 16; ++i) {
        int q = i * 256 + t;
        int bl = q >> 6, k = q & 63;
        T[k][bl] = x[(size_t)(bt * 64 + bl) * NF + k];
    }
    __syncthreads();
    for (int i = 0; i < 16; ++i) {
        int q = i * 256 + t;
        int k = q >> 6, bl = q & 63;
        ws[OFF_XT + (size_t)k * NB + bt * 64 + bl] = T[k][bl];
    }
}

// ---------------------------------------------------------------- A:
// per (btile,n,jhalf): h = relu(X@We2[n]+be2), fused reduce to attnraw[t][6]
// and global h-sum partials. h never hits memory.
__global__ __launch_bounds__(256, 2) void kA(float* __restrict__ ws) {
    __shared__ float Xs[64][128];    // [k][b]
    __shared__ float Wsh[64][128];   // [k][j]
    const int bt = blockIdx.x;       // 0..31 (128 rows each)
    const int n  = blockIdx.y;       // 0..63
    const int jh = blockIdx.z;       // 0..1 (128 j each)
    const int t  = threadIdx.x;

    {   // stage We2 half-tile (coalesced float4)
        const float4* src = (const float4*)(ws + OFF_WE2);
        float4* dst = (float4*)(&Wsh[0][0]);
        #pragma unroll
        for (int i = 0; i < 8; ++i) {
            int q = i * 256 + t;             // 0..2047
            int k = q >> 5, jj = q & 31;
            dst[q] = src[((size_t)(n * NF + k)) * (NH / 4) + jh * 32 + jj];
        }
    }
    {   // stage Xt rows (coalesced, conflict-free LDS writes)
        const float* Xt = ws + OFF_XT;
        #pragma unroll
        for (int i = 0; i < 32; ++i) {
            int q = i * 256 + t;             // 0..8191
            int k = q >> 7, b = q & 127;
            Xs[k][b] = Xt[(size_t)k * NB + bt * 128 + b];
        }
    }
    __syncthreads();

    const int jg = t & 15, bg = t >> 4;
    const int j0 = jg * 8, b0 = bg * 8;
    float acc[8][8];
    #pragma unroll
    for (int bi = 0; bi < 8; ++bi)
        #pragma unroll
        for (int ji = 0; ji < 8; ++ji) acc[bi][ji] = 0.f;

    for (int k = 0; k < 64; ++k) {
        float4 x0 = *(const float4*)&Xs[k][b0];
        float4 x1 = *(const float4*)&Xs[k][b0 + 4];
        float4 w0 = *(const float4*)&Wsh[k][j0];
        float4 w1 = *(const float4*)&Wsh[k][j0 + 4];
        float xv[8] = {x0.x, x0.y, x0.z, x0.w, x1.x, x1.y, x1.z, x1.w};
        float wv[8] = {w0.x, w0.y, w0.z, w0.w, w1.x, w1.y, w1.z, w1.w};
        #pragma unroll
        for (int bi = 0; bi < 8; ++bi)
            #pragma unroll
            for (int ji = 0; ji < 8; ++ji)
                acc[bi][ji] = fmaf(xv[bi], wv[ji], acc[bi][ji]);
    }

    // epilogue: +bias, relu, h-sum, 6-wide Wattn reduction
    const float* be2p  = ws + OFF_BE2 + n * NH + jh * 128;
    const float* Wattn = ws + OFF_WATTN + (jh * 128) * NA;
    float att[8][6];
    #pragma unroll
    for (int bi = 0; bi < 8; ++bi)
        #pragma unroll
        for (int a = 0; a < 6; ++a) att[bi][a] = 0.f;
    float hs = 0.f;
    #pragma unroll
    for (int ji = 0; ji < 8; ++ji) {
        int j = j0 + ji;
        float be = be2p[j];
        float wa[6];
        #pragma unroll
        for (int a = 0; a < 6; ++a) wa[a] = Wattn[j * NA + a];
        #pragma unroll
        for (int bi = 0; bi < 8; ++bi) {
            float h = fmaxf(acc[bi][ji] + be, 0.f);
            hs += h;
            #pragma unroll
            for (int a = 0; a < 6; ++a) att[bi][a] = fmaf(h, wa[a], att[bi][a]);
        }
    }
    // butterfly over the 16 jg lanes (same bg within each 16-lane group)
    #pragma unroll
    for (int m = 1; m <= 8; m <<= 1) {
        #pragma unroll
        for (int bi = 0; bi < 8; ++bi)
            #pragma unroll
            for (int a = 0; a < 6; ++a) att[bi][a] += __shfl_xor(att[bi][a], m, 64);
        hs += __shfl_xor(hs, m, 64);
    }
    hs += __shfl_xor(hs, 16, 64);
    hs += __shfl_xor(hs, 32, 64);

    const int lane = t & 63;
    if ((lane & 15) == 0) {
        float* araw = ws + OFF_ARAW + (size_t)jh * ((size_t)NT * NA);
        #pragma unroll
        for (int bi = 0; bi < 8; ++bi) {
            int b = bt * 128 + b0 + bi;
            size_t tk = (size_t)b * NN + n;
            #pragma unroll
            for (int a = 0; a < 6; ++a) araw[tk * NA + a] = att[bi][a];
        }
    }
    if (lane == 0) atomicAdd(ws + OFF_S + n, hs);
}

// ---------------------------------------------------------------- B:
// scalar gate chain -> c = c1*g
__global__ void kB(float* __restrict__ ws,
                   const float* __restrict__ mW1, const float* __restrict__ mb1,
                   const float* __restrict__ mW2, const float* __restrict__ mb2,
                   const float* __restrict__ gW1, const float* __restrict__ gb1,
                   const float* __restrict__ gW2, const float* __restrict__ gb2) {
    if (threadIdx.x != 0) return;
    float S = 0.f;
    for (int i = 0; i < 64; ++i) S += ws[OFF_S + i];
    float s = S / ((float)NB * NN * NH);
    float accm = mb2[0];
    for (int i = 0; i < 8; ++i) accm += fmaxf(s * mW1[i] + mb1[i], 0.f) * mW2[i];
    float m = 1.f / (1.f + expf(-accm));
    float state = 0.9f * 0.5f + 0.1f * m;
    float c1 = 1.f + 0.1f * (state - 0.5f);
    float sg = c1 * s;
    float accg = gb2[0];
    for (int i = 0; i < 16; ++i) accg += fmaxf(sg * gW1[i] + gb1[i], 0.f) * gW2[i];
    float g = 1.f / (1.f + expf(-accg));
    ws[OFF_C] = c1 * g;
}

// ---------------------------------------------------------------- C:
// attn = c*(araw0+araw1)+battn -> softmax(6) -> clip(w@basis) -> out
__global__ void kC(const float* __restrict__ ws, const float* __restrict__ basis,
                   float* __restrict__ out) {
    const int gid = blockIdx.x * 256 + threadIdx.x;   // one float4 of output
    const int tk = gid >> 5;
    const int e0 = (gid & 31) * 4;
    const float c = ws[OFF_C];
    const float* a0 = ws + OFF_ARAW + (size_t)tk * NA;
    const float* a1 = a0 + (size_t)NT * NA;
    float at[6];
    float mx = -1e30f;
    #pragma unroll
    for (int a = 0; a < 6; ++a) {
        at[a] = fmaf(c, a0[a] + a1[a], ws[OFF_BATTN + a]);
        mx = fmaxf(mx, at[a]);
    }
    float ex[6], ssum = 0.f;
    #pragma unroll
    for (int a = 0; a < 6; ++a) { ex[a] = expf(at[a] - mx); ssum += ex[a]; }
    const float inv = 1.f / ssum;
    float o0 = 0.f, o1 = 0.f, o2 = 0.f, o3 = 0.f;
    #pragma unroll
    for (int a = 0; a < 6; ++a) {
        float w = ex[a] * inv;
        float4 bb = *(const float4*)&basis[a * NE + e0];
        o0 = fmaf(w, bb.x, o0); o1 = fmaf(w, bb.y, o1);
        o2 = fmaf(w, bb.z, o2); o3 = fmaf(w, bb.w, o3);
    }
    float4 r;
    r.x = fminf(fmaxf(o0, -3.f), 3.f);
    r.y = fminf(fmaxf(o1, -3.f), 3.f);
    r.z = fminf(fmaxf(o2, -3.f), 3.f);
    r.w = fminf(fmaxf(o3, -3.f), 3.f);
    *(float4*)&out[(size_t)tk * NE + e0] = r;
}

extern "C" void kernel_launch(void* const* d_in, const int* in_sizes, int n_in,
                              void* d_out, int out_size, void* d_ws, size_t ws_size,
                              hipStream_t stream) {
    const float* x     = (const float*)d_in[0];
    const float* Wemb  = (const float*)d_in[1];
    const float* bemb  = (const float*)d_in[2];
    const float* adjw  = (const float*)d_in[3];
    const float* W1    = (const float*)d_in[4];
    const float* b1    = (const float*)d_in[5];
    const float* W2    = (const float*)d_in[6];
    const float* b2    = (const float*)d_in[7];
    const float* basis = (const float*)d_in[8];
    const float* Wq    = (const float*)d_in[9];
    const float* Wk    = (const float*)d_in[10];
    const float* mW1   = (const float*)d_in[11];
    const float* mb1   = (const float*)d_in[12];
    const float* mW2   = (const float*)d_in[13];
    const float* mb2   = (const float*)d_in[14];
    const float* gW1   = (const float*)d_in[15];
    const float* gb1   = (const float*)d_in[16];
    const float* gW2   = (const float*)d_in[17];
    const float* gb2   = (const float*)d_in[18];
    float* ws  = (float*)d_ws;
    float* out = (float*)d_out;

    kP1<<<1, 256, 0, stream>>>(adjw, basis, Wq, Wk, W2, b2, ws);
    kP2<<<64, 256, 0, stream>>>(Wemb, bemb, ws);
    kP3<<<dim3(64, 16), 256, 0, stream>>>(W1, b1, ws);
    kP4<<<64, 256, 0, stream>>>(x, ws);
    kA<<<dim3(32, 64, 2), 256, 0, stream>>>(ws);
    kB<<<1, 64, 0, stream>>>(ws, mW1, mb1, mW2, mb2, gW1, gb1, gW2, gb2);
    kC<<<NT * NE / 4 / 256, 256, 0, stream>>>(ws, basis, out);
}

// Round 2
// 314.770 us; speedup vs baseline: 1.2309x; 1.2309x over previous
//
#include <hip/hip_runtime.h>
#include <math.h>

#define NN 64      // nodes
#define NF 64      // input features (= K of main GEMM)
#define NE 128     // embed
#define NH 256     // hidden
#define NA 6       // atoms
#define NB 4096    // batch
#define NT (NB*NN) // tokens = 262144

// ---- workspace layout (float offsets) ----
#define OFF_ADJ    0u         // 64*64
#define OFF_WMIX   4096u      // 64*64*128
#define OFF_BMIX   528384u    // 64*128
#define OFF_BE2    536576u    // 64*256 fp32
#define OFF_BATTN  552960u    // 6 (pad 8)
#define OFF_S      552968u    // 64
#define OFF_C      553032u    // 1 (pad 8)
#define OFF_WATTNF 553040u    // 4096 bf16 = 2048 floats (A-frag layout, 16 a-rows)
#define OFF_XBF    555088u    // 4096*64 bf16 = 131072 floats (row-major)
#define OFF_WE2F   686160u    // 64*256*64 bf16 = 2097152 floats (A-frag layout)
#define OFF_ARAW   2783312u   // 262144*8 fp32
// end 4880464 floats = 19.5 MB

typedef __attribute__((ext_vector_type(8))) short short8;
typedef __attribute__((ext_vector_type(4))) float f32x4;

static __device__ __forceinline__ unsigned short bf16r(float f) {
    unsigned u = __float_as_uint(f);
    return (unsigned short)((u + 0x7FFFu + ((u >> 16) & 1u)) >> 16);
}
static __device__ __forceinline__ unsigned bfpack(float lo, float hi) {
    return (unsigned)bf16r(lo) | ((unsigned)bf16r(hi) << 16);
}

// ---------------------------------------------------------------- P1:
// adj (sigmoid*mask, row-normalized), Wattn -> bf16 A-frag layout (+ones col),
// battn, zero S
__global__ void kP1(const float* __restrict__ adjw, const float* __restrict__ basis,
                    const float* __restrict__ Wq, const float* __restrict__ Wk,
                    const float* __restrict__ W2, const float* __restrict__ b2,
                    float* __restrict__ ws) {
    __shared__ float Ks[NA * NE];    // K[a][e2]
    __shared__ float WqK[NE * NA];   // [e][a]
    const int t = threadIdx.x;

    if (t < NN) {
        int r = t >> 3, c = t & 7;
        float sum = 0.f;
        for (int m = 0; m < NN; ++m) {
            int mr = m >> 3, mc = m & 7;
            int man = abs(mr - r) + abs(mc - c);
            float v = 0.f;
            if (man == 1) v = 1.f / (1.f + expf(-adjw[t * NN + m]));
            ws[OFF_ADJ + t * NN + m] = v;
            sum += v;
        }
        float inv = 1.f / fmaxf(sum, 1e-6f);
        for (int m = 0; m < NN; ++m) ws[OFF_ADJ + t * NN + m] *= inv;
    }
    for (int q = t; q < NA * NE; q += 256) {
        int a = q >> 7, e2 = q & 127;
        float acc = 0.f;
        for (int e = 0; e < NE; ++e) acc = fmaf(basis[a * NE + e], Wk[e * NE + e2], acc);
        Ks[a * NE + e2] = acc;
    }
    __syncthreads();
    for (int q = t; q < NE * NA; q += 256) {
        int e = q / NA, a = q - e * NA;
        float acc = 0.f;
        for (int e2 = 0; e2 < NE; ++e2) acc = fmaf(Wq[e * NE + e2], Ks[a * NE + e2], acc);
        WqK[e * NA + a] = acc;
    }
    __syncthreads();
    const float scale = 1.f / (sqrtf(128.f) + 1e-8f);
    {   // Wattn row j = t; write bf16 A-frag layout: [jb][kq][a16][e8]
        float wa[6];
        #pragma unroll
        for (int a = 0; a < NA; ++a) {
            float acc = 0.f;
            for (int e = 0; e < NE; ++e) acc = fmaf(W2[t * NE + e], WqK[e * NA + a], acc);
            wa[a] = acc * scale;
        }
        unsigned short* wf = (unsigned short*)(ws + OFF_WATTNF);
        int jb = t >> 5, kq = (t >> 3) & 3, e = t & 7;
        #pragma unroll
        for (int a = 0; a < 16; ++a) {
            unsigned short v = 0;
            if (a < 6) v = bf16r(wa[a]);
            else if (a == 6) v = bf16r(1.0f);   // ones column -> row-sum of h
            wf[(size_t)((jb * 4 + kq) * 16 + a) * 8 + e] = v;
        }
    }
    if (t < NA) {
        float acc = 0.f;
        for (int e = 0; e < NE; ++e) acc = fmaf(b2[e], WqK[e * NA + t], acc);
        ws[OFF_BATTN + t] = acc * scale;
    }
    if (t < 64) ws[OFF_S + t] = 0.f;
}

// ---------------------------------------------------------------- P2:
// Wmix[n][f][e] = sum_m adj[n,m]*W_embed[f, m*128+e] ; bmix[n][e]
__global__ void kP2(const float* __restrict__ Wemb, const float* __restrict__ bemb,
                    float* __restrict__ ws) {
    __shared__ float adjs[NN];
    const int n = blockIdx.x, t = threadIdx.x;
    if (t < NN) adjs[t] = ws[OFF_ADJ + n * NN + t];
    __syncthreads();
    for (int i = 0; i < 32; ++i) {
        int q = i * 256 + t;
        int f = q >> 7, e = q & 127;
        float acc = 0.f;
        for (int m = 0; m < NN; ++m) {
            float a = adjs[m];
            if (a != 0.f) acc = fmaf(a, Wemb[(size_t)f * (NN * NE) + m * NE + e], acc);
        }
        ws[OFF_WMIX + ((size_t)n * NF + f) * NE + e] = acc;
    }
    if (t < NE) {
        float acc = 0.f;
        for (int m = 0; m < NN; ++m) {
            float a = adjs[m];
            if (a != 0.f) acc = fmaf(a, bemb[m * NE + t], acc);
        }
        ws[OFF_BMIX + n * NE + t] = acc;
    }
}

// ---------------------------------------------------------------- P3:
// We2[n][k][j] = sum_e Wmix[n][k][e]*W1[e][j] -> bf16 A-frag layout
// We2fA[n][j][kk][kq][e8] ; be2 fp32
__global__ void kP3(const float* __restrict__ W1, const float* __restrict__ b1,
                    float* __restrict__ ws) {
    __shared__ float rows[4 * NE];
    __shared__ float brow[NE];
    const int n = blockIdx.x, fb = blockIdx.y * 4, t = threadIdx.x;
    for (int i = 0; i < 2; ++i) {
        int q = i * 256 + t;
        rows[q] = ws[OFF_WMIX + ((size_t)n * NF + fb) * NE + q];
    }
    const bool doB = (blockIdx.y == 0);
    if (doB && t < NE) brow[t] = ws[OFF_BMIX + n * NE + t];
    __syncthreads();
    float acc[4] = {0.f, 0.f, 0.f, 0.f};
    float accb = 0.f;
    for (int e = 0; e < NE; ++e) {
        float w = W1[e * NH + t];
        #pragma unroll
        for (int f = 0; f < 4; ++f) acc[f] = fmaf(rows[f * NE + e], w, acc[f]);
        if (doB) accb = fmaf(brow[e], w, accb);
    }
    unsigned short* wf = (unsigned short*)(ws + OFF_WE2F);
    const int kk = fb >> 5, kq = (fb >> 3) & 3, e0 = fb & 7;
    size_t base = ((((size_t)n * 256 + t) * 2 + kk) * 4 + kq) * 8 + e0;
    #pragma unroll
    for (int f = 0; f < 4; ++f) wf[base + f] = bf16r(acc[f]);
    if (doB) ws[OFF_BE2 + n * NH + t] = accb + b1[t];
}

// ---------------------------------------------------------------- Xbf:
// x fp32 -> bf16 row-major [4096][64]
__global__ void kXbf(const float* __restrict__ x, float* __restrict__ ws) {
    int g = blockIdx.x * 256 + threadIdx.x;    // 65536 threads * 4 elems
    float4 v = ((const float4*)x)[g];
    unsigned* dst = (unsigned*)(ws + OFF_XBF);
    dst[g * 2 + 0] = bfpack(v.x, v.y);
    dst[g * 2 + 1] = bfpack(v.z, v.w);
}

// ---------------------------------------------------------------- A:
// per (bt,n): GEMM1 (MFMA, no LDS): hT[j=256][b=64] = We2^T @ x^T, relu+bias;
// GEMM2 (MFMA): attnT[a][b] += Wattn^T @ hT (ones col -> hsum).
__global__ __launch_bounds__(256) void kA(float* __restrict__ ws) {
    const int bt = blockIdx.x, n = blockIdx.y;
    const int t = threadIdx.x, w = t >> 6, l = t & 63, lo = l & 15, hi = l >> 4;
    const int b0 = bt * 64, j0 = w * 64;
    __shared__ float be2s[256];
    __shared__ float red[4][16][64];

    be2s[t] = ws[OFF_BE2 + n * NH + t];

    const short8* Af = (const short8*)(ws + OFF_WE2F);
    const short8* Bf = (const short8*)(ws + OFF_XBF);
    short8 afr[4][2], bfr[4][2];
    #pragma unroll
    for (int mf = 0; mf < 4; ++mf)
        #pragma unroll
        for (int kk = 0; kk < 2; ++kk)
            afr[mf][kk] = Af[(size_t)n * 2048 + (size_t)(j0 + mf * 16 + lo) * 8 + kk * 4 + hi];
    #pragma unroll
    for (int nf = 0; nf < 4; ++nf)
        #pragma unroll
        for (int kk = 0; kk < 2; ++kk)
            bfr[nf][kk] = Bf[(size_t)(b0 + nf * 16 + lo) * 8 + kk * 4 + hi];

    f32x4 zero = {0.f, 0.f, 0.f, 0.f};
    f32x4 acc[4][4];
    #pragma unroll
    for (int mf = 0; mf < 4; ++mf)
        #pragma unroll
        for (int nf = 0; nf < 4; ++nf) acc[mf][nf] = zero;

    #pragma unroll
    for (int kk = 0; kk < 2; ++kk)
        #pragma unroll
        for (int mf = 0; mf < 4; ++mf)
            #pragma unroll
            for (int nf = 0; nf < 4; ++nf)
                acc[mf][nf] = __builtin_amdgcn_mfma_f32_16x16x32_bf16(
                    afr[mf][kk], bfr[nf][kk], acc[mf][nf], 0, 0, 0);

    __syncthreads();   // be2s ready

    // h = relu(acc + be2[j]); pack to bf16 pairs. lane: row j = j0+mf*16+hi*4+i, col b = nf*16+lo
    unsigned P[4][4][2];
    #pragma unroll
    for (int mf = 0; mf < 4; ++mf) {
        const int jb = j0 + mf * 16 + hi * 4;
        #pragma unroll
        for (int nf = 0; nf < 4; ++nf) {
            float h0 = fmaxf(acc[mf][nf][0] + be2s[jb + 0], 0.f);
            float h1 = fmaxf(acc[mf][nf][1] + be2s[jb + 1], 0.f);
            float h2 = fmaxf(acc[mf][nf][2] + be2s[jb + 2], 0.f);
            float h3 = fmaxf(acc[mf][nf][3] + be2s[jb + 3], 0.f);
            P[mf][nf][0] = bfpack(h0, h1);
            P[mf][nf][1] = bfpack(h2, h3);
        }
    }

    // GEMM2: attnT[a16][b64] over this wave's 64 j's (K=64 -> 2 steps of 32)
    const short8* Wf = (const short8*)(ws + OFF_WATTNF);
    f32x4 acc2[4];
    #pragma unroll
    for (int nf = 0; nf < 4; ++nf) acc2[nf] = zero;
    #pragma unroll
    for (int kk2 = 0; kk2 < 2; ++kk2) {
        short8 a2 = Wf[(size_t)((w * 2 + kk2) * 4 + hi) * 16 + lo];
        #pragma unroll
        for (int nf = 0; nf < 4; ++nf) {
            // B-frag: lane elem i -> hT[kk2*32 + hi*8 + i][nf*16+lo], from D-layout P via shuffles
            unsigned bq[4];
            #pragma unroll
            for (int q = 0; q < 4; ++q) {
                int s = ((hi & 1) * 2 + (q >> 1)) * 16 + lo;
                unsigned vA = (unsigned)__shfl((int)P[2 * kk2 + 0][nf][q & 1], s, 64);
                unsigned vB = (unsigned)__shfl((int)P[2 * kk2 + 1][nf][q & 1], s, 64);
                bq[q] = (hi >= 2) ? vB : vA;
            }
            union { unsigned u[4]; short8 v; } cv;
            cv.u[0] = bq[0]; cv.u[1] = bq[1]; cv.u[2] = bq[2]; cv.u[3] = bq[3];
            acc2[nf] = __builtin_amdgcn_mfma_f32_16x16x32_bf16(a2, cv.v, acc2[nf], 0, 0, 0);
        }
    }

    // cross-wave reduce of attnT partials
    #pragma unroll
    for (int nf = 0; nf < 4; ++nf)
        #pragma unroll
        for (int i = 0; i < 4; ++i)
            red[w][hi * 4 + i][nf * 16 + lo] = acc2[nf][i];
    __syncthreads();

    const int rb = t & 63, a0 = t >> 6, a1 = a0 + 4;
    float v0 = red[0][a0][rb] + red[1][a0][rb] + red[2][a0][rb] + red[3][a0][rb];
    float v1 = red[0][a1][rb] + red[1][a1][rb] + red[2][a1][rb] + red[3][a1][rb];
    float* araw = ws + OFF_ARAW;
    size_t base = ((size_t)(b0 + rb) * 64 + n) * 8;
    araw[base + a0] = v0;                 // a0 in 0..3
    if (a1 < 6) araw[base + a1] = v1;     // a1 = 4,5
    if (a1 == 6) {                        // threads 128..191 = wave 2: hsum
        float hs = v1;
        #pragma unroll
        for (int m = 1; m < 64; m <<= 1) hs += __shfl_xor(hs, m, 64);
        if (l == 0) atomicAdd(ws + OFF_S + n, hs);
    }
}

// ---------------------------------------------------------------- B:
// scalar gate chain -> c = c1*g
__global__ void kB(float* __restrict__ ws,
                   const float* __restrict__ mW1, const float* __restrict__ mb1,
                   const float* __restrict__ mW2, const float* __restrict__ mb2,
                   const float* __restrict__ gW1, const float* __restrict__ gb1,
                   const float* __restrict__ gW2, const float* __restrict__ gb2) {
    if (threadIdx.x != 0) return;
    float S = 0.f;
    for (int i = 0; i < 64; ++i) S += ws[OFF_S + i];
    float s = S / ((float)NB * NN * NH);
    float accm = mb2[0];
    for (int i = 0; i < 8; ++i) accm += fmaxf(s * mW1[i] + mb1[i], 0.f) * mW2[i];
    float m = 1.f / (1.f + expf(-accm));
    float state = 0.9f * 0.5f + 0.1f * m;
    float c1 = 1.f + 0.1f * (state - 0.5f);
    float sg = c1 * s;
    float accg = gb2[0];
    for (int i = 0; i < 16; ++i) accg += fmaxf(sg * gW1[i] + gb1[i], 0.f) * gW2[i];
    float g = 1.f / (1.f + expf(-accg));
    ws[OFF_C] = c1 * g;
}

// ---------------------------------------------------------------- C:
// block = (n, 64-batch chunk): softmax(6) per token, out = clip(w@basis)
__global__ __launch_bounds__(256) void kC(const float* __restrict__ ws,
                                          const float* __restrict__ basis,
                                          float* __restrict__ out) {
    const int n = blockIdx.x, bc = blockIdx.y;
    const int t = threadIdx.x;
    __shared__ float sw[64][6];
    __shared__ float bs[6][128];
    for (int q = t; q < NA * NE; q += 256) bs[q >> 7][q & 127] = basis[q];
    if (t < 64) {
        const float c = ws[OFF_C];
        const float* ar = ws + OFF_ARAW + ((size_t)(bc * 64 + t) * 64 + n) * 8;
        float at[6], mx = -1e30f;
        #pragma unroll
        for (int a = 0; a < 6; ++a) {
            at[a] = fmaf(c, ar[a], ws[OFF_BATTN + a]);
            mx = fmaxf(mx, at[a]);
        }
        float ex[6], ssum = 0.f;
        #pragma unroll
        for (int a = 0; a < 6; ++a) { ex[a] = expf(at[a] - mx); ssum += ex[a]; }
        float inv = 1.f / ssum;
        #pragma unroll
        for (int a = 0; a < 6; ++a) sw[t][a] = ex[a] * inv;
    }
    __syncthreads();
    const int tok = t >> 2, q = t & 3;
    float wv[6];
    #pragma unroll
    for (int a = 0; a < 6; ++a) wv[a] = sw[tok][a];
    float* op = out + ((size_t)(bc * 64 + tok) * 64 + n) * NE + q * 32;
    #pragma unroll
    for (int e8 = 0; e8 < 32; e8 += 4) {
        float4 r;
        #pragma unroll
        for (int cc = 0; cc < 4; ++cc) {
            int e = q * 32 + e8 + cc;
            float o = 0.f;
            #pragma unroll
            for (int a = 0; a < 6; ++a) o = fmaf(wv[a], bs[a][e], o);
            ((float*)&r)[cc] = fminf(fmaxf(o, -3.f), 3.f);
        }
        *(float4*)(op + e8) = r;
    }
}

extern "C" void kernel_launch(void* const* d_in, const int* in_sizes, int n_in,
                              void* d_out, int out_size, void* d_ws, size_t ws_size,
                              hipStream_t stream) {
    const float* x     = (const float*)d_in[0];
    const float* Wemb  = (const float*)d_in[1];
    const float* bemb  = (const float*)d_in[2];
    const float* adjw  = (const float*)d_in[3];
    const float* W1    = (const float*)d_in[4];
    const float* b1    = (const float*)d_in[5];
    const float* W2    = (const float*)d_in[6];
    const float* b2    = (const float*)d_in[7];
    const float* basis = (const float*)d_in[8];
    const float* Wq    = (const float*)d_in[9];
    const float* Wk    = (const float*)d_in[10];
    const float* mW1   = (const float*)d_in[11];
    const float* mb1   = (const float*)d_in[12];
    const float* mW2   = (const float*)d_in[13];
    const float* mb2   = (const float*)d_in[14];
    const float* gW1   = (const float*)d_in[15];
    const float* gb1   = (const float*)d_in[16];
    const float* gW2   = (const float*)d_in[17];
    const float* gb2   = (const float*)d_in[18];
    float* ws  = (float*)d_ws;
    float* out = (float*)d_out;

    kP1<<<1, 256, 0, stream>>>(adjw, basis, Wq, Wk, W2, b2, ws);
    kP2<<<64, 256, 0, stream>>>(Wemb, bemb, ws);
    kP3<<<dim3(64, 16), 256, 0, stream>>>(W1, b1, ws);
    kXbf<<<256, 256, 0, stream>>>(x, ws);
    kA<<<dim3(64, 64), 256, 0, stream>>>(ws);
    kB<<<1, 64, 0, stream>>>(ws, mW1, mb1, mW2, mb2, gW1, gb1, gW2, gb2);
    kC<<<dim3(64, 64), 256, 0, stream>>>(ws, basis, out);
}

// Round 3
// 176.492 us; speedup vs baseline: 2.1953x; 1.7835x over previous
//
#include <hip/hip_runtime.h>
#include <math.h>

#define NN 64      // nodes
#define NF 64      // input features (= K of main GEMM)
#define NE 128     // embed
#define NH 256     // hidden
#define NA 6       // atoms
#define NB 4096    // batch
#define NT (NB*NN) // tokens = 262144

// ---- workspace layout (float offsets) ----
#define OFF_ADJ    0u         // 64*64
#define OFF_GB     4096u      // 64*256   gb[m][j] = bemb_blk_m @ W1
#define OFF_BE2    20480u     // 64*256
#define OFF_BATTN  36864u     // 6 (pad 8)
#define OFF_S      36872u     // 64
#define OFF_C      36936u     // 1 (pad 8)
#define OFF_WATTNF 36944u     // 2048 fl = 4096 bf16 (A-frag, 16 a-rows)
#define OFF_XBF    38992u     // 131072 fl = x bf16 [4096][64]
#define OFF_WE2F   170064u    // 2097152 fl = We2 bf16 A-frag [n][j][k-frag]
#define OFF_ARAW   2267216u   // 2097152 fl = [bt][n][bb][8]
#define OFF_G      OFF_ARAW   // G[m][f][j] 64*64*256 fp32 (consumed before ARAW written)
// end 4364368 floats = 17.5 MB

typedef __attribute__((ext_vector_type(8))) short short8;
typedef __attribute__((ext_vector_type(4))) float f32x4;
typedef __attribute__((ext_vector_type(4))) unsigned short us4;

static __device__ __forceinline__ unsigned short bf16r(float f) {
    unsigned u = __float_as_uint(f);
    return (unsigned short)((u + 0x7FFFu + ((u >> 16) & 1u)) >> 16);
}
static __device__ __forceinline__ unsigned bfpack(float lo, float hi) {
    return (unsigned)bf16r(lo) | ((unsigned)bf16r(hi) << 16);
}

// ---------------------------------------------------------------- Prep1 (fused):
// blocks 0..1023  : G[m][f][j] = Wemb_blk_m @ W1 ; gb[m][j] = bemb_blk_m @ W1
// block  1024     : adj (sigmoid*mask, row-norm), Wattn bf16 A-frag (+ones col),
//                   battn, zero S
// blocks 1025..1280: x -> bf16 row-major
__global__ __launch_bounds__(256) void kPrep1(
        const float* __restrict__ x, const float* __restrict__ Wemb,
        const float* __restrict__ bemb, const float* __restrict__ adjw,
        const float* __restrict__ W1, const float* __restrict__ basis,
        const float* __restrict__ Wq, const float* __restrict__ Wk,
        const float* __restrict__ W2, const float* __restrict__ b2,
        float* __restrict__ ws) {
    __shared__ float shA[768];
    __shared__ float shB[768];
    const int bx = blockIdx.x, t = threadIdx.x;

    if (bx < 1024) {
        // ---- G / gb GEMM slice: m = bx>>4, f-rows fb..fb+3 ----
        const int m = bx >> 4, fb = (bx & 15) * 4;
        float* rows = shA;            // [4][128]
        float* brow = shB;            // [128]
        #pragma unroll
        for (int i = 0; i < 2; ++i) {
            int q = i * 256 + t;
            int f = q >> 7, e = q & 127;
            rows[f * NE + e] = Wemb[(size_t)(fb + f) * (NN * NE) + m * NE + e];
        }
        const bool doB = (fb == 0);
        if (doB && t < NE) brow[t] = bemb[m * NE + t];
        __syncthreads();
        float acc[4] = {0.f, 0.f, 0.f, 0.f};
        float accb = 0.f;
        for (int e = 0; e < NE; ++e) {
            float w = W1[e * NH + t];
            #pragma unroll
            for (int f = 0; f < 4; ++f) acc[f] = fmaf(rows[f * NE + e], w, acc[f]);
            if (doB) accb = fmaf(brow[e], w, accb);
        }
        float* G = ws + OFF_G;
        #pragma unroll
        for (int f = 0; f < 4; ++f)
            G[(size_t)(m * NF + fb + f) * NH + t] = acc[f];
        if (doB) ws[OFF_GB + m * NH + t] = accb;
        return;
    }
    if (bx >= 1025) {
        // ---- x -> bf16 ----
        int g = (bx - 1025) * 256 + t;
        float4 v = ((const float4*)x)[g];
        unsigned* dst = (unsigned*)(ws + OFF_XBF);
        dst[g * 2 + 0] = bfpack(v.x, v.y);
        dst[g * 2 + 1] = bfpack(v.z, v.w);
        return;
    }
    // ---- block 1024: adj + Wattn + battn + zero S ----
    float* Ks  = shA;   // K[a][e2]  (6*128)
    float* WqK = shB;   // [e][a]    (128*6)
    if (t < NN) {
        int r = t >> 3, c = t & 7;
        float sum = 0.f;
        for (int m = 0; m < NN; ++m) {
            int mr = m >> 3, mc = m & 7;
            int man = abs(mr - r) + abs(mc - c);
            float v = 0.f;
            if (man == 1) v = 1.f / (1.f + expf(-adjw[t * NN + m]));
            ws[OFF_ADJ + t * NN + m] = v;
            sum += v;
        }
        float inv = 1.f / fmaxf(sum, 1e-6f);
        for (int m = 0; m < NN; ++m) ws[OFF_ADJ + t * NN + m] *= inv;
    }
    for (int q = t; q < NA * NE; q += 256) {
        int a = q >> 7, e2 = q & 127;
        float acc = 0.f;
        for (int e = 0; e < NE; ++e) acc = fmaf(basis[a * NE + e], Wk[e * NE + e2], acc);
        Ks[a * NE + e2] = acc;
    }
    __syncthreads();
    for (int q = t; q < NE * NA; q += 256) {
        int e = q / NA, a = q - e * NA;
        float acc = 0.f;
        for (int e2 = 0; e2 < NE; ++e2) acc = fmaf(Wq[e * NE + e2], Ks[a * NE + e2], acc);
        WqK[e * NA + a] = acc;
    }
    __syncthreads();
    const float scale = 1.f / (sqrtf(128.f) + 1e-8f);
    {   // Wattn row j = t -> bf16 A-frag [jb][kq][a16][e8]
        float wa[6];
        #pragma unroll
        for (int a = 0; a < NA; ++a) {
            float acc = 0.f;
            for (int e = 0; e < NE; ++e) acc = fmaf(W2[t * NE + e], WqK[e * NA + a], acc);
            wa[a] = acc * scale;
        }
        unsigned short* wf = (unsigned short*)(ws + OFF_WATTNF);
        int jb = t >> 5, kq = (t >> 3) & 3, e = t & 7;
        #pragma unroll
        for (int a = 0; a < 16; ++a) {
            unsigned short v = 0;
            if (a < 6) v = bf16r(wa[a]);
            else if (a == 6) v = bf16r(1.0f);   // ones column -> row-sum of h
            wf[(size_t)((jb * 4 + kq) * 16 + a) * 8 + e] = v;
        }
    }
    if (t < NA) {
        float acc = 0.f;
        for (int e = 0; e < NE; ++e) acc = fmaf(b2[e], WqK[e * NA + t], acc);
        ws[OFF_BATTN + t] = acc * scale;
    }
    if (t < 64) ws[OFF_S + t] = 0.f;
}

// ---------------------------------------------------------------- Sum:
// We2f[n] (bf16 A-frag) = Sum_{4 nbrs} adj[n,m] * G[m]; be2 = Sum adj*gb + b1
__global__ __launch_bounds__(256) void kSum(const float* __restrict__ b1,
                                            float* __restrict__ ws) {
    const int n = blockIdx.x, fb = blockIdx.y * 4, t = threadIdx.x;
    const int r = n >> 3, c = n & 7;
    const float* G = ws + OFF_G;
    float acc[4] = {0.f, 0.f, 0.f, 0.f};
    float accb = 0.f;
    const bool doB = (blockIdx.y == 0);
    #pragma unroll
    for (int d = 0; d < 4; ++d) {
        int m; bool ok;
        if (d == 0)      { m = n - 8; ok = (r > 0); }
        else if (d == 1) { m = n + 8; ok = (r < 7); }
        else if (d == 2) { m = n - 1; ok = (c > 0); }
        else             { m = n + 1; ok = (c < 7); }
        if (ok) {
            float av = ws[OFF_ADJ + n * NN + m];
            #pragma unroll
            for (int f = 0; f < 4; ++f)
                acc[f] = fmaf(av, G[(size_t)(m * NF + fb + f) * NH + t], acc[f]);
            if (doB) accb = fmaf(av, ws[OFF_GB + m * NH + t], accb);
        }
    }
    // frag write: f = fb+f' -> kk=f>>5, kq=(f>>3)&3, e0=f&7 (fb%4==0 so kk,kq,e0base uniform)
    unsigned short* wf = (unsigned short*)(ws + OFF_WE2F);
    const int kk = fb >> 5, kq = (fb >> 3) & 3, e0 = fb & 7;
    us4 pack;
    #pragma unroll
    for (int f = 0; f < 4; ++f) pack[f] = bf16r(acc[f]);
    *(us4*)(wf + ((((size_t)(n * NH + t) * 2 + kk) * 4 + kq) * 8 + e0)) = pack;
    if (doB) ws[OFF_BE2 + n * NH + t] = accb + b1[t];
}

// ---------------------------------------------------------------- A:
// per (bt,n): GEMM1 (MFMA, no LDS): hT[j=256][b=64] = We2^T @ x^T, relu+bias;
// GEMM2 (MFMA): attnT[a][b] = Wattn^T @ hT (ones col -> hsum). araw contiguous.
__global__ __launch_bounds__(256) void kA(float* __restrict__ ws) {
    const int bt = blockIdx.x, n = blockIdx.y;
    const int t = threadIdx.x, w = t >> 6, l = t & 63, lo = l & 15, hi = l >> 4;
    const int b0 = bt * 64, j0 = w * 64;
    __shared__ float be2s[256];
    __shared__ float red[4][16][64];

    be2s[t] = ws[OFF_BE2 + n * NH + t];

    const short8* Af = (const short8*)(ws + OFF_WE2F);
    const short8* Bf = (const short8*)(ws + OFF_XBF);
    short8 afr[4][2], bfr[4][2];
    #pragma unroll
    for (int mf = 0; mf < 4; ++mf)
        #pragma unroll
        for (int kk = 0; kk < 2; ++kk)
            afr[mf][kk] = Af[(size_t)n * 2048 + (size_t)(j0 + mf * 16 + lo) * 8 + kk * 4 + hi];
    #pragma unroll
    for (int nf = 0; nf < 4; ++nf)
        #pragma unroll
        for (int kk = 0; kk < 2; ++kk)
            bfr[nf][kk] = Bf[(size_t)(b0 + nf * 16 + lo) * 8 + kk * 4 + hi];

    f32x4 zero = {0.f, 0.f, 0.f, 0.f};
    f32x4 acc[4][4];
    #pragma unroll
    for (int mf = 0; mf < 4; ++mf)
        #pragma unroll
        for (int nf = 0; nf < 4; ++nf) acc[mf][nf] = zero;

    #pragma unroll
    for (int kk = 0; kk < 2; ++kk)
        #pragma unroll
        for (int mf = 0; mf < 4; ++mf)
            #pragma unroll
            for (int nf = 0; nf < 4; ++nf)
                acc[mf][nf] = __builtin_amdgcn_mfma_f32_16x16x32_bf16(
                    afr[mf][kk], bfr[nf][kk], acc[mf][nf], 0, 0, 0);

    __syncthreads();   // be2s ready

    // h = relu(acc + be2[j]); pack bf16. lane: row j = j0+mf*16+hi*4+i, col b = nf*16+lo
    unsigned P[4][4][2];
    #pragma unroll
    for (int mf = 0; mf < 4; ++mf) {
        const int jb = j0 + mf * 16 + hi * 4;
        #pragma unroll
        for (int nf = 0; nf < 4; ++nf) {
            float h0 = fmaxf(acc[mf][nf][0] + be2s[jb + 0], 0.f);
            float h1 = fmaxf(acc[mf][nf][1] + be2s[jb + 1], 0.f);
            float h2 = fmaxf(acc[mf][nf][2] + be2s[jb + 2], 0.f);
            float h3 = fmaxf(acc[mf][nf][3] + be2s[jb + 3], 0.f);
            P[mf][nf][0] = bfpack(h0, h1);
            P[mf][nf][1] = bfpack(h2, h3);
        }
    }

    // GEMM2: attnT[a16][b64] over this wave's 64 j's (K=64 -> 2 steps of 32)
    const short8* Wf = (const short8*)(ws + OFF_WATTNF);
    f32x4 acc2[4];
    #pragma unroll
    for (int nf = 0; nf < 4; ++nf) acc2[nf] = zero;
    #pragma unroll
    for (int kk2 = 0; kk2 < 2; ++kk2) {
        short8 a2 = Wf[(size_t)((w * 2 + kk2) * 4 + hi) * 16 + lo];
        #pragma unroll
        for (int nf = 0; nf < 4; ++nf) {
            unsigned bq[4];
            #pragma unroll
            for (int q = 0; q < 4; ++q) {
                int s = ((hi & 1) * 2 + (q >> 1)) * 16 + lo;
                unsigned vA = (unsigned)__shfl((int)P[2 * kk2 + 0][nf][q & 1], s, 64);
                unsigned vB = (unsigned)__shfl((int)P[2 * kk2 + 1][nf][q & 1], s, 64);
                bq[q] = (hi >= 2) ? vB : vA;
            }
            union { unsigned u[4]; short8 v; } cv;
            cv.u[0] = bq[0]; cv.u[1] = bq[1]; cv.u[2] = bq[2]; cv.u[3] = bq[3];
            acc2[nf] = __builtin_amdgcn_mfma_f32_16x16x32_bf16(a2, cv.v, acc2[nf], 0, 0, 0);
        }
    }

    // cross-wave reduce
    #pragma unroll
    for (int nf = 0; nf < 4; ++nf)
        #pragma unroll
        for (int i = 0; i < 4; ++i)
            red[w][hi * 4 + i][nf * 16 + lo] = acc2[nf][i];
    __syncthreads();

    const int rb = t & 63, a0 = t >> 6, a1 = a0 + 4;
    float v0 = red[0][a0][rb] + red[1][a0][rb] + red[2][a0][rb] + red[3][a0][rb];
    float v1 = red[0][a1][rb] + red[1][a1][rb] + red[2][a1][rb] + red[3][a1][rb];
    if (a1 == 6) {   // wave 2: ones-column = h row-sums -> global S[n]
        float hs = v1;
        #pragma unroll
        for (int m = 1; m < 64; m <<= 1) hs += __shfl_xor(hs, m, 64);
        if (l == 0) atomicAdd(ws + OFF_S + n, hs);
    }
    __syncthreads();                       // done reading red
    float* red2 = &red[0][0][0];           // [64][8]
    red2[rb * 8 + a0] = v0;
    red2[rb * 8 + a1] = v1;
    __syncthreads();
    if (t < 128) {                         // contiguous 2 KB block write
        float4 v = ((const float4*)red2)[t];
        ((float4*)(ws + OFF_ARAW))[(size_t)(bt * 64 + n) * 128 + t] = v;
    }
}

// ---------------------------------------------------------------- B:
// scalar gate chain -> c = c1*g
__global__ void kB(float* __restrict__ ws,
                   const float* __restrict__ mW1, const float* __restrict__ mb1,
                   const float* __restrict__ mW2, const float* __restrict__ mb2,
                   const float* __restrict__ gW1, const float* __restrict__ gb1,
                   const float* __restrict__ gW2, const float* __restrict__ gb2) {
    if (threadIdx.x != 0) return;
    float S = 0.f;
    for (int i = 0; i < 64; ++i) S += ws[OFF_S + i];
    float s = S / ((float)NB * NN * NH);
    float accm = mb2[0];
    for (int i = 0; i < 8; ++i) accm += fmaxf(s * mW1[i] + mb1[i], 0.f) * mW2[i];
    float m = 1.f / (1.f + expf(-accm));
    float state = 0.9f * 0.5f + 0.1f * m;
    float c1 = 1.f + 0.1f * (state - 0.5f);
    float sg = c1 * s;
    float accg = gb2[0];
    for (int i = 0; i < 16; ++i) accg += fmaxf(sg * gW1[i] + gb1[i], 0.f) * gW2[i];
    float g = 1.f / (1.f + expf(-accg));
    ws[OFF_C] = c1 * g;
}

// ---------------------------------------------------------------- C:
// block = one batch row b: softmax(6) for its 64 tokens, write 32 KB
// contiguous output row: out[b][n*128+e] = clip(w@basis).
__global__ __launch_bounds__(256) void kC(const float* __restrict__ ws,
                                          const float* __restrict__ basis,
                                          float* __restrict__ out) {
    const int b = blockIdx.x, bt = b >> 6, bb = b & 63;
    const int t = threadIdx.x;
    __shared__ float sw[64][8];
    __shared__ float bs[6][128];
    for (int q = t; q < NA * NE; q += 256) bs[q >> 7][q & 127] = basis[q];
    if (t < 64) {
        const float c = ws[OFF_C];
        const float* ar = ws + OFF_ARAW + ((size_t)(bt * 64 + t) * 64 + bb) * 8;
        float at[6], mx = -1e30f;
        #pragma unroll
        for (int a = 0; a < 6; ++a) {
            at[a] = fmaf(c, ar[a], ws[OFF_BATTN + a]);
            mx = fmaxf(mx, at[a]);
        }
        float ex[6], ssum = 0.f;
        #pragma unroll
        for (int a = 0; a < 6; ++a) { ex[a] = expf(at[a] - mx); ssum += ex[a]; }
        float inv = 1.f / ssum;
        #pragma unroll
        for (int a = 0; a < 6; ++a) sw[t][a] = ex[a] * inv;
    }
    __syncthreads();
    float* op = out + (size_t)b * (NN * NE);
    #pragma unroll
    for (int i = 0; i < 8; ++i) {            // dense 1KB-per-wave-instr writes
        int idx = i * 1024 + t * 4;          // 0..8191
        int n = idx >> 7, e = idx & 127;
        float wv[6];
        #pragma unroll
        for (int a = 0; a < 6; ++a) wv[a] = sw[n][a];
        float4 r;
        #pragma unroll
        for (int cc = 0; cc < 4; ++cc) {
            float o = 0.f;
            #pragma unroll
            for (int a = 0; a < 6; ++a) o = fmaf(wv[a], bs[a][e + cc], o);
            ((float*)&r)[cc] = fminf(fmaxf(o, -3.f), 3.f);
        }
        *(float4*)(op + idx) = r;
    }
}

extern "C" void kernel_launch(void* const* d_in, const int* in_sizes, int n_in,
                              void* d_out, int out_size, void* d_ws, size_t ws_size,
                              hipStream_t stream) {
    const float* x     = (const float*)d_in[0];
    const float* Wemb  = (const float*)d_in[1];
    const float* bemb  = (const float*)d_in[2];
    const float* adjw  = (const float*)d_in[3];
    const float* W1    = (const float*)d_in[4];
    const float* b1    = (const float*)d_in[5];
    const float* W2    = (const float*)d_in[6];
    const float* b2    = (const float*)d_in[7];
    const float* basis = (const float*)d_in[8];
    const float* Wq    = (const float*)d_in[9];
    const float* Wk    = (const float*)d_in[10];
    const float* mW1   = (const float*)d_in[11];
    const float* mb1   = (const float*)d_in[12];
    const float* mW2   = (const float*)d_in[13];
    const float* mb2   = (const float*)d_in[14];
    const float* gW1   = (const float*)d_in[15];
    const float* gb1   = (const float*)d_in[16];
    const float* gW2   = (const float*)d_in[17];
    const float* gb2   = (const float*)d_in[18];
    float* ws  = (float*)d_ws;
    float* out = (float*)d_out;

    kPrep1<<<1281, 256, 0, stream>>>(x, Wemb, bemb, adjw, W1, basis, Wq, Wk, W2, b2, ws);
    kSum<<<dim3(64, 16), 256, 0, stream>>>(b1, ws);
    kA<<<dim3(64, 64), 256, 0, stream>>>(ws);
    kB<<<1, 64, 0, stream>>>(ws, mW1, mb1, mW2, mb2, gW1, gb1, gW2, gb2);
    kC<<<NB, 256, 0, stream>>>(ws, basis, out);
}

// Round 4
// 152.365 us; speedup vs baseline: 2.5430x; 1.1583x over previous
//
#include <hip/hip_runtime.h>
#include <math.h>

#define NN 64      // nodes
#define NF 64      // input features (= K of main GEMM)
#define NE 128     // embed
#define NH 256     // hidden
#define NA 6       // atoms
#define NB 4096    // batch
#define NT (NB*NN) // tokens = 262144

// ---- workspace layout (float offsets) ----
#define OFF_BE2    20480u     // 64*256 fp32
#define OFF_BATTN  36864u     // 6 (pad 8)
#define OFF_S      36872u     // 64
#define OFF_WATTNF 36944u     // 2048 fl = 4096 bf16 (GEMM2 A-frag: [j>>3][a16][j&7])
#define OFF_XBF    38992u     // 131072 fl = x bf16 [4096][64]
#define OFF_WE2F   170064u    // 2097152 fl = We2^T bf16 [n][j][f] row-major
#define OFF_ARAW   2267216u   // 2097152 fl = [bt*64+n][64 b][8 a]
// end 4364368 floats = 17.5 MB

typedef __attribute__((ext_vector_type(8))) short short8;
typedef __attribute__((ext_vector_type(4))) float f32x4;
typedef __attribute__((ext_vector_type(4))) unsigned short us4;

static __device__ __forceinline__ unsigned short bf16r(float f) {
    unsigned u = __float_as_uint(f);
    return (unsigned short)((u + 0x7FFFu + ((u >> 16) & 1u)) >> 16);
}
static __device__ __forceinline__ unsigned bfpack(float lo, float hi) {
    return (unsigned)bf16r(lo) | ((unsigned)bf16r(hi) << 16);
}

// ---------------------------------------------------------------- kP (fused prep):
// blocks 0..255  : (n = bx>>2, jq = bx&3): inline-adj -> Wmix[n] in LDS ->
//                  fp32 GEMM -> We2^T bf16 [n][j][f] + be2 fp32
// blocks 256..511: x -> bf16 row-major
// block  512     : Wattn bf16 frag (+ones col), battn, zero S
__global__ __launch_bounds__(256) void kP(
        const float* __restrict__ x, const float* __restrict__ Wemb,
        const float* __restrict__ bemb, const float* __restrict__ adjw,
        const float* __restrict__ W1, const float* __restrict__ b1,
        const float* __restrict__ basis, const float* __restrict__ Wq,
        const float* __restrict__ Wk, const float* __restrict__ W2,
        const float* __restrict__ b2, float* __restrict__ ws) {
    __shared__ float sh[9792];
    const int bx = blockIdx.x, t = threadIdx.x;

    if (bx < 256) {
        // ---- We2 GEMM block: n, j-quarter ----
        const int n = bx >> 2, jq = bx & 3;
        float* Wm = sh;              // [64][128] fp32 Wmix
        float* bm = sh + 8192;       // [128] bmix
        const int r = n >> 3, c = n & 7;
        int ml[4]; int nm = 0;
        if (r > 0) ml[nm++] = n - 8;
        if (r < 7) ml[nm++] = n + 8;
        if (c > 0) ml[nm++] = n - 1;
        if (c < 7) ml[nm++] = n + 1;
        float av[4]; float asum = 0.f;
        for (int d = 0; d < nm; ++d) {
            av[d] = 1.f / (1.f + expf(-adjw[n * NN + ml[d]]));
            asum += av[d];
        }
        const float ainv = 1.f / fmaxf(asum, 1e-6f);
        for (int d = 0; d < nm; ++d) av[d] *= ainv;

        for (int i = 0; i < 32; ++i) {
            int idx = i * 256 + t;
            int f = idx >> 7, e = idx & 127;
            float acc = 0.f;
            for (int d = 0; d < nm; ++d)
                acc = fmaf(av[d], Wemb[(size_t)f * (NN * NE) + ml[d] * NE + e], acc);
            Wm[f * 128 + e] = acc;
        }
        if (t < 128) {
            float accb = 0.f;
            for (int d = 0; d < nm; ++d)
                accb = fmaf(av[d], bemb[ml[d] * NE + t], accb);
            bm[t] = accb;
        }
        __syncthreads();

        const int fg = t >> 6, jl = t & 63, j = jq * 64 + jl;
        float acc[16];
        #pragma unroll
        for (int i = 0; i < 16; ++i) acc[i] = 0.f;
        float accb = 0.f;
        const float* w1p = W1 + j;
        const float* wmp = Wm + fg * 2048;     // 16 f-rows per wave (broadcast reads)
        for (int e0 = 0; e0 < 128; e0 += 4) {
            float w10 = w1p[(e0 + 0) * NH];
            float w11 = w1p[(e0 + 1) * NH];
            float w12 = w1p[(e0 + 2) * NH];
            float w13 = w1p[(e0 + 3) * NH];
            #pragma unroll
            for (int fi = 0; fi < 16; ++fi) {
                float4 wm = *(const float4*)&wmp[fi * 128 + e0];
                acc[fi] = fmaf(wm.x, w10, fmaf(wm.y, w11, fmaf(wm.z, w12, fmaf(wm.w, w13, acc[fi]))));
            }
            if (fg == 0) {
                float4 bv = *(const float4*)&bm[e0];
                accb = fmaf(bv.x, w10, fmaf(bv.y, w11, fmaf(bv.z, w12, fmaf(bv.w, w13, accb))));
            }
        }
        unsigned short* wf = (unsigned short*)(ws + OFF_WE2F) + (((size_t)n * NH + j) * 64 + fg * 16);
        #pragma unroll
        for (int p4 = 0; p4 < 4; ++p4) {
            us4 pk;
            #pragma unroll
            for (int k = 0; k < 4; ++k) pk[k] = bf16r(acc[p4 * 4 + k]);
            *(us4*)(wf + p4 * 4) = pk;
        }
        if (fg == 0) ws[OFF_BE2 + n * NH + j] = accb + b1[j];
        return;
    }
    if (bx < 512) {
        // ---- x -> bf16 ----
        int g = (bx - 256) * 256 + t;
        float4 v = ((const float4*)x)[g];
        unsigned* dst = (unsigned*)(ws + OFF_XBF);
        dst[g * 2 + 0] = bfpack(v.x, v.y);
        dst[g * 2 + 1] = bfpack(v.z, v.w);
        return;
    }
    // ---- block 512: Wattn + battn + zero S ----
    float* Ks   = sh;            // [6][128]
    float* WqK  = sh + 768;      // [128][6]
    float* Tile = sh + 1536;     // [64][129] staging (pad -> conflict-free)
    unsigned* wfz = (unsigned*)(ws + OFF_WATTNF);
    for (int q = t; q < 2048; q += 256) wfz[q] = 0u;
    if (t < 64) ws[OFF_S + t] = 0.f;
    for (int q = t; q < NA * NE; q += 256) {
        int a = q >> 7, e2 = q & 127;
        float acc = 0.f;
        for (int e = 0; e < NE; ++e) acc = fmaf(basis[a * NE + e], Wk[e * NE + e2], acc);
        Ks[a * NE + e2] = acc;
    }
    const int jl = t & 63, ag = t >> 6;
    const int na = (ag < 2) ? 2 : 1;          // a in {ag, ag+4}
    for (int et = 0; et < 2; ++et) {
        __syncthreads();
        for (int i = 0; i < 32; ++i) {
            int idx = i * 256 + t;
            int er = idx >> 7, e2 = idx & 127;
            Tile[er * 129 + e2] = Wq[(et * 64 + er) * NE + e2];
        }
        __syncthreads();
        int e = et * 64 + jl;
        for (int ai = 0; ai < na; ++ai) {
            int a = ag + ai * 4;
            float acc = 0.f;
            for (int e2 = 0; e2 < NE; ++e2)
                acc = fmaf(Tile[jl * 129 + e2], Ks[a * NE + e2], acc);
            WqK[e * NA + a] = acc;
        }
    }
    const float scale = 1.f / (sqrtf(128.f) + 1e-8f);
    unsigned short* wf16 = (unsigned short*)(ws + OFF_WATTNF);
    for (int jt = 0; jt < 4; ++jt) {
        __syncthreads();
        for (int i = 0; i < 32; ++i) {
            int idx = i * 256 + t;
            int jr = idx >> 7, e = idx & 127;
            Tile[jr * 129 + e] = W2[(jt * 64 + jr) * NE + e];
        }
        __syncthreads();
        int j = jt * 64 + jl;
        for (int ai = 0; ai < na; ++ai) {
            int a = ag + ai * 4;
            float acc = 0.f;
            for (int e = 0; e < NE; ++e)
                acc = fmaf(Tile[jl * 129 + e], WqK[e * NA + a], acc);
            wf16[((j >> 3) * 16 + a) * 8 + (j & 7)] = bf16r(acc * scale);
        }
        if (ag == 3) wf16[((j >> 3) * 16 + 6) * 8 + (j & 7)] = bf16r(1.0f);  // ones col
    }
    __syncthreads();
    if (t < NA) {
        float acc = 0.f;
        for (int e = 0; e < NE; ++e) acc = fmaf(b2[e], WqK[e * NA + t], acc);
        ws[OFF_BATTN + t] = acc * scale;
    }
}

// ---------------------------------------------------------------- A:
// per (bt,n): GEMM1 (MFMA, no LDS): hT[j=256][b=64] = We2^T @ x^T, relu+bias;
// GEMM2 (MFMA): attnT[a][b] = Wattn^T @ hT (ones col -> hsum). araw contiguous.
__global__ __launch_bounds__(256) void kA(float* __restrict__ ws) {
    const int bt = blockIdx.x, n = blockIdx.y;
    const int t = threadIdx.x, w = t >> 6, l = t & 63, lo = l & 15, hi = l >> 4;
    const int b0 = bt * 64, j0 = w * 64;
    __shared__ float be2s[256];
    __shared__ float red[4][16][64];

    be2s[t] = ws[OFF_BE2 + n * NH + t];

    const short8* Af = (const short8*)(ws + OFF_WE2F);
    const short8* Bf = (const short8*)(ws + OFF_XBF);
    short8 afr[4][2], bfr[4][2];
    #pragma unroll
    for (int mf = 0; mf < 4; ++mf)
        #pragma unroll
        for (int kk = 0; kk < 2; ++kk)
            afr[mf][kk] = Af[(size_t)n * 2048 + (size_t)(j0 + mf * 16 + lo) * 8 + kk * 4 + hi];
    #pragma unroll
    for (int nf = 0; nf < 4; ++nf)
        #pragma unroll
        for (int kk = 0; kk < 2; ++kk)
            bfr[nf][kk] = Bf[(size_t)(b0 + nf * 16 + lo) * 8 + kk * 4 + hi];

    f32x4 zero = {0.f, 0.f, 0.f, 0.f};
    f32x4 acc[4][4];
    #pragma unroll
    for (int mf = 0; mf < 4; ++mf)
        #pragma unroll
        for (int nf = 0; nf < 4; ++nf) acc[mf][nf] = zero;

    #pragma unroll
    for (int kk = 0; kk < 2; ++kk)
        #pragma unroll
        for (int mf = 0; mf < 4; ++mf)
            #pragma unroll
            for (int nf = 0; nf < 4; ++nf)
                acc[mf][nf] = __builtin_amdgcn_mfma_f32_16x16x32_bf16(
                    afr[mf][kk], bfr[nf][kk], acc[mf][nf], 0, 0, 0);

    __syncthreads();   // be2s ready

    // h = relu(acc + be2[j]); pack bf16. lane: row j = j0+mf*16+hi*4+i, col b = nf*16+lo
    unsigned P[4][4][2];
    #pragma unroll
    for (int mf = 0; mf < 4; ++mf) {
        const int jb = j0 + mf * 16 + hi * 4;
        #pragma unroll
        for (int nf = 0; nf < 4; ++nf) {
            float h0 = fmaxf(acc[mf][nf][0] + be2s[jb + 0], 0.f);
            float h1 = fmaxf(acc[mf][nf][1] + be2s[jb + 1], 0.f);
            float h2 = fmaxf(acc[mf][nf][2] + be2s[jb + 2], 0.f);
            float h3 = fmaxf(acc[mf][nf][3] + be2s[jb + 3], 0.f);
            P[mf][nf][0] = bfpack(h0, h1);
            P[mf][nf][1] = bfpack(h2, h3);
        }
    }

    // GEMM2: attnT[a16][b64] over this wave's 64 j's (K=64 -> 2 steps of 32)
    const short8* Wf = (const short8*)(ws + OFF_WATTNF);
    f32x4 acc2[4];
    #pragma unroll
    for (int nf = 0; nf < 4; ++nf) acc2[nf] = zero;
    #pragma unroll
    for (int kk2 = 0; kk2 < 2; ++kk2) {
        short8 a2 = Wf[(size_t)((w * 2 + kk2) * 4 + hi) * 16 + lo];
        #pragma unroll
        for (int nf = 0; nf < 4; ++nf) {
            unsigned bq[4];
            #pragma unroll
            for (int q = 0; q < 4; ++q) {
                int s = ((hi & 1) * 2 + (q >> 1)) * 16 + lo;
                unsigned vA = (unsigned)__shfl((int)P[2 * kk2 + 0][nf][q & 1], s, 64);
                unsigned vB = (unsigned)__shfl((int)P[2 * kk2 + 1][nf][q & 1], s, 64);
                bq[q] = (hi >= 2) ? vB : vA;
            }
            union { unsigned u[4]; short8 v; } cv;
            cv.u[0] = bq[0]; cv.u[1] = bq[1]; cv.u[2] = bq[2]; cv.u[3] = bq[3];
            acc2[nf] = __builtin_amdgcn_mfma_f32_16x16x32_bf16(a2, cv.v, acc2[nf], 0, 0, 0);
        }
    }

    // cross-wave reduce
    #pragma unroll
    for (int nf = 0; nf < 4; ++nf)
        #pragma unroll
        for (int i = 0; i < 4; ++i)
            red[w][hi * 4 + i][nf * 16 + lo] = acc2[nf][i];
    __syncthreads();

    const int rb = t & 63, a0 = t >> 6, a1 = a0 + 4;
    float v0 = red[0][a0][rb] + red[1][a0][rb] + red[2][a0][rb] + red[3][a0][rb];
    float v1 = red[0][a1][rb] + red[1][a1][rb] + red[2][a1][rb] + red[3][a1][rb];
    if (a1 == 6) {   // wave 2: ones-column = h row-sums -> global S[n]
        float hs = v1;
        #pragma unroll
        for (int m = 1; m < 64; m <<= 1) hs += __shfl_xor(hs, m, 64);
        if (l == 0) atomicAdd(ws + OFF_S + n, hs);
    }
    __syncthreads();                       // done reading red
    float* red2 = &red[0][0][0];           // [64][8]
    red2[rb * 8 + a0] = v0;
    red2[rb * 8 + a1] = v1;
    __syncthreads();
    if (t < 128) {                         // contiguous 2 KB block write
        float4 v = ((const float4*)red2)[t];
        ((float4*)(ws + OFF_ARAW))[(size_t)(bt * 64 + n) * 128 + t] = v;
    }
}

// ---------------------------------------------------------------- C:
// block = one batch row b: thread0 computes scalar gate chain (c), 64 threads
// do softmax(6) for the row's 64 tokens, all write 32 KB contiguous output.
__global__ __launch_bounds__(256) void kC(const float* __restrict__ ws,
                                          const float* __restrict__ basis,
                                          const float* __restrict__ mW1, const float* __restrict__ mb1,
                                          const float* __restrict__ mW2, const float* __restrict__ mb2,
                                          const float* __restrict__ gW1, const float* __restrict__ gb1,
                                          const float* __restrict__ gW2, const float* __restrict__ gb2,
                                          float* __restrict__ out) {
    const int b = blockIdx.x, bt = b >> 6, bb = b & 63;
    const int t = threadIdx.x;
    __shared__ float sw[64][8];
    __shared__ float bs[6][128];
    __shared__ float csh;
    for (int q = t; q < NA * NE; q += 256) bs[q >> 7][q & 127] = basis[q];
    if (t == 0) {   // scalar gate chain (ex-kB), hidden under basis staging
        float S = 0.f;
        for (int i = 0; i < 64; ++i) S += ws[OFF_S + i];
        float s = S / ((float)NB * NN * NH);
        float accm = mb2[0];
        for (int i = 0; i < 8; ++i) accm += fmaxf(s * mW1[i] + mb1[i], 0.f) * mW2[i];
        float m = 1.f / (1.f + expf(-accm));
        float state = 0.9f * 0.5f + 0.1f * m;
        float c1 = 1.f + 0.1f * (state - 0.5f);
        float sg = c1 * s;
        float accg = gb2[0];
        for (int i = 0; i < 16; ++i) accg += fmaxf(sg * gW1[i] + gb1[i], 0.f) * gW2[i];
        float g = 1.f / (1.f + expf(-accg));
        csh = c1 * g;
    }
    __syncthreads();
    if (t < 64) {
        const float c = csh;
        const float* ar = ws + OFF_ARAW + ((size_t)(bt * 64 + t) * 64 + bb) * 8;
        float at[6], mx = -1e30f;
        #pragma unroll
        for (int a = 0; a < 6; ++a) {
            at[a] = fmaf(c, ar[a], ws[OFF_BATTN + a]);
            mx = fmaxf(mx, at[a]);
        }
        float ex[6], ssum = 0.f;
        #pragma unroll
        for (int a = 0; a < 6; ++a) { ex[a] = expf(at[a] - mx); ssum += ex[a]; }
        float inv = 1.f / ssum;
        #pragma unroll
        for (int a = 0; a < 6; ++a) sw[t][a] = ex[a] * inv;
    }
    __syncthreads();
    float* op = out + (size_t)b * (NN * NE);
    #pragma unroll
    for (int i = 0; i < 8; ++i) {
        int idx = i * 1024 + t * 4;          // 0..8191
        int n = idx >> 7, e = idx & 127;
        float wv[6];
        #pragma unroll
        for (int a = 0; a < 6; ++a) wv[a] = sw[n][a];
        float4 r;
        #pragma unroll
        for (int cc = 0; cc < 4; ++cc) {
            float o = 0.f;
            #pragma unroll
            for (int a = 0; a < 6; ++a) o = fmaf(wv[a], bs[a][e + cc], o);
            ((float*)&r)[cc] = fminf(fmaxf(o, -3.f), 3.f);
        }
        *(float4*)(op + idx) = r;
    }
}

extern "C" void kernel_launch(void* const* d_in, const int* in_sizes, int n_in,
                              void* d_out, int out_size, void* d_ws, size_t ws_size,
                              hipStream_t stream) {
    const float* x     = (const float*)d_in[0];
    const float* Wemb  = (const float*)d_in[1];
    const float* bemb  = (const float*)d_in[2];
    const float* adjw  = (const float*)d_in[3];
    const float* W1    = (const float*)d_in[4];
    const float* b1    = (const float*)d_in[5];
    const float* W2    = (const float*)d_in[6];
    const float* b2    = (const float*)d_in[7];
    const float* basis = (const float*)d_in[8];
    const float* Wq    = (const float*)d_in[9];
    const float* Wk    = (const float*)d_in[10];
    const float* mW1   = (const float*)d_in[11];
    const float* mb1   = (const float*)d_in[12];
    const float* mW2   = (const float*)d_in[13];
    const float* mb2   = (const float*)d_in[14];
    const float* gW1   = (const float*)d_in[15];
    const float* gb1   = (const float*)d_in[16];
    const float* gW2   = (const float*)d_in[17];
    const float* gb2   = (const float*)d_in[18];
    float* ws  = (float*)d_ws;
    float* out = (float*)d_out;

    kP<<<513, 256, 0, stream>>>(x, Wemb, bemb, adjw, W1, b1, basis, Wq, Wk, W2, b2, ws);
    kA<<<dim3(64, 64), 256, 0, stream>>>(ws);
    kC<<<NB, 256, 0, stream>>>(ws, basis, mW1, mb1, mW2, mb2, gW1, gb1, gW2, gb2, out);
}

// Round 5
// 134.882 us; speedup vs baseline: 2.8726x; 1.1296x over previous
//
#include <hip/hip_runtime.h>
#include <math.h>

#define NN 64      // nodes
#define NF 64      // input features (= K of main GEMM)
#define NE 128     // embed
#define NH 256     // hidden
#define NA 6       // atoms
#define NB 4096    // batch
#define NT (NB*NN) // tokens = 262144

// ---- workspace layout (float offsets) ----
#define OFF_BE2    20480u     // 64*256 fp32
#define OFF_BATTN  36864u     // 6 (pad 8)
#define OFF_S      36872u     // 64
#define OFF_WATTNF 36944u     // 2048 fl = 4096 bf16 (GEMM2 A-frag: [j>>3][a16][j&7])
#define OFF_XBF    38992u     // 131072 fl = x bf16 in B-frag order [bt][nf][kk][l][8]
#define OFF_WE2F   170064u    // 2097152 fl = We2 bf16 in A-frag order [n][w][mf][kk][l][8]
#define OFF_ARAW   2267216u   // 2097152 fl = [b][n][8]
// end 4364368 floats = 17.5 MB

typedef __attribute__((ext_vector_type(8))) short short8;
typedef __attribute__((ext_vector_type(4))) float f32x4;
typedef __attribute__((ext_vector_type(4))) unsigned short us4;

static __device__ __forceinline__ unsigned short bf16r(float f) {
    unsigned u = __float_as_uint(f);
    return (unsigned short)((u + 0x7FFFu + ((u >> 16) & 1u)) >> 16);
}
static __device__ __forceinline__ unsigned bfpack(float lo, float hi) {
    return (unsigned)bf16r(lo) | ((unsigned)bf16r(hi) << 16);
}

// ---------------------------------------------------------------- kP (fused prep):
// bx 0..255   : (n = bx>>2, jq = bx&3) We2 GEMM -> frag-order bf16 + be2 fp32
// bx 256..383 : x -> bf16 in B-frag order
// bx 384..387 : Wattn (jt = bx-384) -> frag order; 384 also battn + zero S
__global__ __launch_bounds__(256) void kP(
        const float* __restrict__ x, const float* __restrict__ Wemb,
        const float* __restrict__ bemb, const float* __restrict__ adjw,
        const float* __restrict__ W1, const float* __restrict__ b1,
        const float* __restrict__ basis, const float* __restrict__ Wq,
        const float* __restrict__ Wk, const float* __restrict__ W2,
        const float* __restrict__ b2, float* __restrict__ ws) {
    __shared__ float sh[17024];
    const int bx = blockIdx.x, t = threadIdx.x;

    if (bx < 256) {
        // ---- We2 GEMM block: n, j-quarter (64 j x 64 f, K=128) ----
        const int n = bx >> 2, jq = bx & 3;
        float* WmT = sh;              // [128 e][68]  (transposed mix, padded)
        float* W1q = sh + 8704;       // [128 e][64 j]
        float* bm  = sh + 16896;      // [128 e]
        const int r = n >> 3, c = n & 7;
        int ml[4]; int nm = 0;
        if (r > 0) ml[nm++] = n - 8;
        if (r < 7) ml[nm++] = n + 8;
        if (c > 0) ml[nm++] = n - 1;
        if (c < 7) ml[nm++] = n + 1;
        float av[4]; float asum = 0.f;
        for (int d = 0; d < nm; ++d) {
            av[d] = 1.f / (1.f + expf(-adjw[n * NN + ml[d]]));
            asum += av[d];
        }
        const float ainv = 1.f / fmaxf(asum, 1e-6f);
        for (int d = 0; d < nm; ++d) av[d] *= ainv;

        #pragma unroll 4
        for (int i = 0; i < 32; ++i) {              // WmT[e][f]
            int idx = i * 256 + t;
            int f = idx >> 7, e = idx & 127;
            float acc = 0.f;
            for (int d = 0; d < nm; ++d)
                acc = fmaf(av[d], Wemb[(size_t)f * (NN * NE) + ml[d] * NE + e], acc);
            WmT[e * 68 + f] = acc;
        }
        if (t < 128) {
            float accb = 0.f;
            for (int d = 0; d < nm; ++d)
                accb = fmaf(av[d], bemb[ml[d] * NE + t], accb);
            bm[t] = accb;
        }
        #pragma unroll 4
        for (int i = 0; i < 32; ++i) {              // W1q[e][j]
            int idx = i * 256 + t;
            int e = idx >> 6, j6 = idx & 63;
            W1q[e * 64 + j6] = W1[(size_t)e * NH + jq * 64 + j6];
        }
        __syncthreads();

        const int jg = t & 15, fg = t >> 4;         // j-quad, f-quad
        float acc[4][4];
        #pragma unroll
        for (int jj = 0; jj < 4; ++jj)
            #pragma unroll
            for (int ff = 0; ff < 4; ++ff) acc[jj][ff] = 0.f;
        float accb[4] = {0.f, 0.f, 0.f, 0.f};
        #pragma unroll 2
        for (int e = 0; e < 128; ++e) {
            float4 w1 = *(const float4*)&W1q[e * 64 + jg * 4];
            float4 wm = *(const float4*)&WmT[e * 68 + fg * 4];
            const float w1v[4] = {w1.x, w1.y, w1.z, w1.w};
            const float wmv[4] = {wm.x, wm.y, wm.z, wm.w};
            #pragma unroll
            for (int jj = 0; jj < 4; ++jj)
                #pragma unroll
                for (int ff = 0; ff < 4; ++ff)
                    acc[jj][ff] = fmaf(w1v[jj], wmv[ff], acc[jj][ff]);
            if (fg == 0) {
                float bb = bm[e];
                #pragma unroll
                for (int jj = 0; jj < 4; ++jj) accb[jj] = fmaf(bb, w1v[jj], accb[jj]);
            }
        }
        // frag-order write: chunk(j, c=f>>3) at [n][jq][mf][kk][l=(c&3)*16+(j&15)]
        unsigned short* wf = (unsigned short*)(ws + OFF_WE2F);
        const int mf = jg >> 2, kk = fg >> 3, lbase = ((fg >> 1) & 3) * 16;
        const size_t cb = ((((size_t)n * 4 + jq) * 4 + mf) * 2 + kk) * 64;
        #pragma unroll
        for (int jj = 0; jj < 4; ++jj) {
            int jl = jg * 4 + jj;
            size_t off = (cb + lbase + (jl & 15)) * 8 + (fg & 1) * 4;
            us4 pk;
            #pragma unroll
            for (int ff = 0; ff < 4; ++ff) pk[ff] = bf16r(acc[jj][ff]);
            *(us4*)(wf + off) = pk;
        }
        if (fg == 0) {
            #pragma unroll
            for (int jj = 0; jj < 4; ++jj) {
                int j = jq * 64 + jg * 4 + jj;
                ws[OFF_BE2 + n * NH + j] = accb[jj] + b1[j];
            }
        }
        return;
    }
    if (bx < 384) {
        // ---- x -> bf16 B-frag order ----
        int g = (bx - 256) * 256 + t;               // 0..32767
        int b = g >> 3, ko = g & 7;
        float4 v0 = ((const float4*)x)[b * 16 + ko * 2];
        float4 v1 = ((const float4*)x)[b * 16 + ko * 2 + 1];
        union { unsigned u[4]; short8 v; } cv;
        cv.u[0] = bfpack(v0.x, v0.y); cv.u[1] = bfpack(v0.z, v0.w);
        cv.u[2] = bfpack(v1.x, v1.y); cv.u[3] = bfpack(v1.z, v1.w);
        int bt = b >> 6, nf = (b >> 4) & 3, kk = ko >> 2, l = (ko & 3) * 16 + (b & 15);
        ((short8*)(ws + OFF_XBF))[(((size_t)bt * 4 + nf) * 2 + kk) * 64 + l] = cv.v;
        return;
    }
    // ---- Wattn blocks: jt = bx-384 handles j = jt*64..+63 ----
    const int jt = bx - 384;
    float* Ks  = sh;            // [6][128]
    float* WqK = sh + 768;      // [128][8] (pad)
    float* W2t = sh + 1792;     // [64][129]
    for (int q = t; q < NA * NE; q += 256) {
        int a = q >> 7, e2 = q & 127;
        float acc = 0.f;
        for (int e = 0; e < NE; ++e) acc = fmaf(basis[a * NE + e], Wk[e * NE + e2], acc);
        Ks[a * NE + e2] = acc;
    }
    __syncthreads();
    for (int q = t; q < NE * NA; q += 256) {
        int e = q / NA, a = q - e * NA;
        float acc = 0.f;
        for (int e2 = 0; e2 < NE; ++e2) acc = fmaf(Wq[e * NE + e2], Ks[a * NE + e2], acc);
        WqK[e * 8 + a] = acc;
    }
    __syncthreads();
    for (int i = 0; i < 32; ++i) {                  // stage W2 rows jt*64..+63
        int idx = i * 256 + t;
        int jr = idx >> 7, e = idx & 127;
        W2t[jr * 129 + e] = W2[(size_t)(jt * 64 + jr) * NE + e];
    }
    __syncthreads();
    const float scale = 1.f / (sqrtf(128.f) + 1e-8f);
    unsigned short* wf16 = (unsigned short*)(ws + OFF_WATTNF);
    const int jl = t & 63, ag = t >> 6;
    const int j = jt * 64 + jl;
    const int na = (ag < 2) ? 2 : 1;
    for (int ai = 0; ai < na; ++ai) {
        int a = ag + ai * 4;
        float acc = 0.f;
        for (int e = 0; e < NE; ++e)
            acc = fmaf(W2t[jl * 129 + e], WqK[e * 8 + a], acc);
        wf16[((j >> 3) * 16 + a) * 8 + (j & 7)] = bf16r(acc * scale);
    }
    if (ag == 3) wf16[((j >> 3) * 16 + 6) * 8 + (j & 7)] = bf16r(1.0f);  // ones col
    for (int a7 = 7 + ag; a7 < 16; a7 += 4)
        wf16[((j >> 3) * 16 + a7) * 8 + (j & 7)] = 0;
    if (jt == 0) {
        __syncthreads();
        if (t < NA) {
            float acc = 0.f;
            for (int e = 0; e < NE; ++e) acc = fmaf(b2[e], WqK[e * 8 + t], acc);
            ws[OFF_BATTN + t] = acc * scale;
        }
        if (t < 64) ws[OFF_S + t] = 0.f;
    }
}

// ---------------------------------------------------------------- A:
// per (bt,n): GEMM1 (MFMA, frag loads fully coalesced): hT = We2^T @ x^T,
// relu+bias; GEMM2 (MFMA): attnT[a][b] (ones col -> hsum). ARAW [b][n][8].
__global__ __launch_bounds__(256) void kA(float* __restrict__ ws) {
    const int bt = blockIdx.x, n = blockIdx.y;
    const int t = threadIdx.x, w = t >> 6, l = t & 63, lo = l & 15, hi = l >> 4;
    const int j0 = w * 64;
    __shared__ float be2s[256];
    __shared__ float red[4][16][64];

    be2s[t] = ws[OFF_BE2 + n * NH + t];

    const short8* Af = (const short8*)(ws + OFF_WE2F);
    const short8* Bf = (const short8*)(ws + OFF_XBF);
    short8 afr[4][2], bfr[4][2];
    #pragma unroll
    for (int mf = 0; mf < 4; ++mf)
        #pragma unroll
        for (int kk = 0; kk < 2; ++kk)
            afr[mf][kk] = Af[(((size_t)n * 4 + w) * 4 + mf) * 2 * 64 + (size_t)kk * 64 + l];
    #pragma unroll
    for (int nf = 0; nf < 4; ++nf)
        #pragma unroll
        for (int kk = 0; kk < 2; ++kk)
            bfr[nf][kk] = Bf[(((size_t)bt * 4 + nf) * 2 + kk) * 64 + l];

    f32x4 zero = {0.f, 0.f, 0.f, 0.f};
    f32x4 acc[4][4];
    #pragma unroll
    for (int mf = 0; mf < 4; ++mf)
        #pragma unroll
        for (int nf = 0; nf < 4; ++nf) acc[mf][nf] = zero;

    #pragma unroll
    for (int kk = 0; kk < 2; ++kk)
        #pragma unroll
        for (int mf = 0; mf < 4; ++mf)
            #pragma unroll
            for (int nf = 0; nf < 4; ++nf)
                acc[mf][nf] = __builtin_amdgcn_mfma_f32_16x16x32_bf16(
                    afr[mf][kk], bfr[nf][kk], acc[mf][nf], 0, 0, 0);

    __syncthreads();   // be2s ready

    // h = relu(acc + be2[j]); pack bf16. lane: row j = j0+mf*16+hi*4+i, col b = nf*16+lo
    unsigned P[4][4][2];
    #pragma unroll
    for (int mf = 0; mf < 4; ++mf) {
        const int jb = j0 + mf * 16 + hi * 4;
        #pragma unroll
        for (int nf = 0; nf < 4; ++nf) {
            float h0 = fmaxf(acc[mf][nf][0] + be2s[jb + 0], 0.f);
            float h1 = fmaxf(acc[mf][nf][1] + be2s[jb + 1], 0.f);
            float h2 = fmaxf(acc[mf][nf][2] + be2s[jb + 2], 0.f);
            float h3 = fmaxf(acc[mf][nf][3] + be2s[jb + 3], 0.f);
            P[mf][nf][0] = bfpack(h0, h1);
            P[mf][nf][1] = bfpack(h2, h3);
        }
    }

    // GEMM2: attnT[a16][b64] over this wave's 64 j's (K=64 -> 2 steps of 32)
    const short8* Wf = (const short8*)(ws + OFF_WATTNF);
    f32x4 acc2[4];
    #pragma unroll
    for (int nf = 0; nf < 4; ++nf) acc2[nf] = zero;
    #pragma unroll
    for (int kk2 = 0; kk2 < 2; ++kk2) {
        short8 a2 = Wf[(size_t)(w * 2 + kk2) * 64 + l];
        #pragma unroll
        for (int nf = 0; nf < 4; ++nf) {
            unsigned bq[4];
            #pragma unroll
            for (int q = 0; q < 4; ++q) {
                int s = ((hi & 1) * 2 + (q >> 1)) * 16 + lo;
                unsigned vA = (unsigned)__shfl((int)P[2 * kk2 + 0][nf][q & 1], s, 64);
                unsigned vB = (unsigned)__shfl((int)P[2 * kk2 + 1][nf][q & 1], s, 64);
                bq[q] = (hi >= 2) ? vB : vA;
            }
            union { unsigned u[4]; short8 v; } cv;
            cv.u[0] = bq[0]; cv.u[1] = bq[1]; cv.u[2] = bq[2]; cv.u[3] = bq[3];
            acc2[nf] = __builtin_amdgcn_mfma_f32_16x16x32_bf16(a2, cv.v, acc2[nf], 0, 0, 0);
        }
    }

    // cross-wave reduce
    #pragma unroll
    for (int nf = 0; nf < 4; ++nf)
        #pragma unroll
        for (int i = 0; i < 4; ++i)
            red[w][hi * 4 + i][nf * 16 + lo] = acc2[nf][i];
    __syncthreads();

    const int rb = t & 63, a0 = t >> 6, a1 = a0 + 4;
    float v0 = red[0][a0][rb] + red[1][a0][rb] + red[2][a0][rb] + red[3][a0][rb];
    float v1 = red[0][a1][rb] + red[1][a1][rb] + red[2][a1][rb] + red[3][a1][rb];
    if (a1 == 6) {   // wave 2: ones-column = h row-sums -> global S[n]
        float hs = v1;
        #pragma unroll
        for (int m = 1; m < 64; m <<= 1) hs += __shfl_xor(hs, m, 64);
        if (l == 0) atomicAdd(ws + OFF_S + n, hs);
    }
    __syncthreads();                       // done reading red
    float* red2 = &red[0][0][0];           // [64 b][8 a]
    red2[rb * 8 + a0] = v0;
    red2[rb * 8 + a1] = v1;
    __syncthreads();
    if (t < 128) {                         // ARAW[b][n][8]
        int i = t >> 1, half = t & 1;
        float4 v = *(const float4*)&red2[i * 8 + half * 4];
        *(float4*)(ws + OFF_ARAW + ((size_t)(bt * 64 + i) * 64 + n) * 8 + half * 4) = v;
    }
}

// ---------------------------------------------------------------- C:
// block = one batch row b: thread0 scalar gate chain (c), contiguous 2 KB
// ARAW read via LDS, softmax(6) per token, 32 KB contiguous output write.
__global__ __launch_bounds__(256) void kC(const float* __restrict__ ws,
                                          const float* __restrict__ basis,
                                          const float* __restrict__ mW1, const float* __restrict__ mb1,
                                          const float* __restrict__ mW2, const float* __restrict__ mb2,
                                          const float* __restrict__ gW1, const float* __restrict__ gb1,
                                          const float* __restrict__ gW2, const float* __restrict__ gb2,
                                          float* __restrict__ out) {
    const int b = blockIdx.x;
    const int t = threadIdx.x;
    __shared__ float ars[512];
    __shared__ float sw[64][8];
    __shared__ float bs[6][128];
    __shared__ float csh;
    if (t < 128)
        ((float4*)ars)[t] = ((const float4*)(ws + OFF_ARAW + (size_t)b * 512))[t];
    for (int q = t; q < NA * NE; q += 256) bs[q >> 7][q & 127] = basis[q];
    if (t == 0) {   // scalar gate chain
        float S = 0.f;
        for (int i = 0; i < 64; ++i) S += ws[OFF_S + i];
        float s = S / ((float)NB * NN * NH);
        float accm = mb2[0];
        for (int i = 0; i < 8; ++i) accm += fmaxf(s * mW1[i] + mb1[i], 0.f) * mW2[i];
        float m = 1.f / (1.f + expf(-accm));
        float state = 0.9f * 0.5f + 0.1f * m;
        float c1 = 1.f + 0.1f * (state - 0.5f);
        float sg = c1 * s;
        float accg = gb2[0];
        for (int i = 0; i < 16; ++i) accg += fmaxf(sg * gW1[i] + gb1[i], 0.f) * gW2[i];
        float g = 1.f / (1.f + expf(-accg));
        csh = c1 * g;
    }
    __syncthreads();
    if (t < 64) {
        const float c = csh;
        float at[6], mx = -1e30f;
        #pragma unroll
        for (int a = 0; a < 6; ++a) {
            at[a] = fmaf(c, ars[t * 8 + a], ws[OFF_BATTN + a]);
            mx = fmaxf(mx, at[a]);
        }
        float ex[6], ssum = 0.f;
        #pragma unroll
        for (int a = 0; a < 6; ++a) { ex[a] = expf(at[a] - mx); ssum += ex[a]; }
        float inv = 1.f / ssum;
        #pragma unroll
        for (int a = 0; a < 6; ++a) sw[t][a] = ex[a] * inv;
    }
    __syncthreads();
    float* op = out + (size_t)b * (NN * NE);
    #pragma unroll
    for (int i = 0; i < 8; ++i) {
        int idx = i * 1024 + t * 4;          // 0..8191
        int n = idx >> 7, e = idx & 127;
        float wv[6];
        #pragma unroll
        for (int a = 0; a < 6; ++a) wv[a] = sw[n][a];
        float4 r;
        #pragma unroll
        for (int cc = 0; cc < 4; ++cc) {
            float o = 0.f;
            #pragma unroll
            for (int a = 0; a < 6; ++a) o = fmaf(wv[a], bs[a][e + cc], o);
            ((float*)&r)[cc] = fminf(fmaxf(o, -3.f), 3.f);
        }
        *(float4*)(op + idx) = r;
    }
}

extern "C" void kernel_launch(void* const* d_in, const int* in_sizes, int n_in,
                              void* d_out, int out_size, void* d_ws, size_t ws_size,
                              hipStream_t stream) {
    const float* x     = (const float*)d_in[0];
    const float* Wemb  = (const float*)d_in[1];
    const float* bemb  = (const float*)d_in[2];
    const float* adjw  = (const float*)d_in[3];
    const float* W1    = (const float*)d_in[4];
    const float* b1    = (const float*)d_in[5];
    const float* W2    = (const float*)d_in[6];
    const float* b2    = (const float*)d_in[7];
    const float* basis = (const float*)d_in[8];
    const float* Wq    = (const float*)d_in[9];
    const float* Wk    = (const float*)d_in[10];
    const float* mW1   = (const float*)d_in[11];
    const float* mb1   = (const float*)d_in[12];
    const float* mW2   = (const float*)d_in[13];
    const float* mb2   = (const float*)d_in[14];
    const float* gW1   = (const float*)d_in[15];
    const float* gb1   = (const float*)d_in[16];
    const float* gW2   = (const float*)d_in[17];
    const float* gb2   = (const float*)d_in[18];
    float* ws  = (float*)d_ws;
    float* out = (float*)d_out;

    kP<<<388, 256, 0, stream>>>(x, Wemb, bemb, adjw, W1, b1, basis, Wq, Wk, W2, b2, ws);
    kA<<<dim3(64, 64), 256, 0, stream>>>(ws);
    kC<<<NB, 256, 0, stream>>>(ws, basis, mW1, mb1, mW2, mb2, gW1, gb1, gW2, gb2, out);
}

// Round 6
// 102.353 us; speedup vs baseline: 3.7855x; 1.3178x over previous
//
#include <hip/hip_runtime.h>
#include <math.h>

#define NN 64      // nodes
#define NF 64      // input features (= K of main GEMM)
#define NE 128     // embed
#define NH 256     // hidden
#define NA 6       // atoms
#define NB 4096    // batch

// ---- workspace layout (float offsets) ----
#define OFF_WATTN16 8192u    // 2048 fl: Wattn 16x16x16 A-frag [jt][mf][l][4 bf16]
#define OFF_BE2    20480u    // 64*256 fp32
#define OFF_BATTN  36864u    // 6 (pad 8)
#define OFF_S      36872u    // 64
#define OFF_WATTNF 36944u    // 2048 fl: fallback 16x16x32 A-frag
#define OFF_XBF    38992u    // 131072 fl = x bf16 B-frag order [bt][nf][kk][l][8]
#define OFF_WE2F   170064u   // 2097152 fl = We2 bf16 A-frag order [n][w][mf][kk][l][8]
#define OFF_ARAW   2267216u  // 2097152 fl = [b][n][8]

typedef __attribute__((ext_vector_type(8))) short short8;
typedef __attribute__((ext_vector_type(4))) short short4v;
typedef __attribute__((ext_vector_type(4))) float f32x4;

#if __has_builtin(__builtin_amdgcn_mfma_f32_16x16x16bf16_1k)
#define USE_MFMA16 1
#else
#define USE_MFMA16 0
#endif

static __device__ __forceinline__ unsigned short bf16r(float f) {
    unsigned u = __float_as_uint(f);
    return (unsigned short)((u + 0x7FFFu + ((u >> 16) & 1u)) >> 16);
}
static __device__ __forceinline__ unsigned bfpack(float lo, float hi) {
    return (unsigned)bf16r(lo) | ((unsigned)bf16r(hi) << 16);
}
static __device__ __forceinline__ unsigned cvtpk(float lo, float hi) {
    unsigned r;
    asm("v_cvt_pk_bf16_f32 %0, %1, %2" : "=v"(r) : "v"(lo), "v"(hi));
    return r;
}

// ---------------------------------------------------------------- kP (fused prep, 512 thr):
// bx 0..255   : (n = bx>>2, jq = bx&3) We2 GEMM -> frag-order bf16 + be2 fp32
// bx 256..319 : x -> bf16 in B-frag order
// bx 320..323 : Wattn (jt) -> both frag layouts; jt==0 also battn + zero S
__global__ __launch_bounds__(512) void kP(
        const float* __restrict__ x, const float* __restrict__ Wemb,
        const float* __restrict__ bemb, const float* __restrict__ adjw,
        const float* __restrict__ W1, const float* __restrict__ b1,
        const float* __restrict__ basis, const float* __restrict__ Wq,
        const float* __restrict__ Wk, const float* __restrict__ W2,
        const float* __restrict__ b2, float* __restrict__ ws) {
    __shared__ float sh[17024];
    const int bx = blockIdx.x, t = threadIdx.x;

    if (bx < 256) {
        // ---- We2 GEMM block: n, j-quarter (64 j x 64 f, K=128) ----
        const int n = bx >> 2, jq = bx & 3;
        float* WmT = sh;              // [128 e][68]  (transposed mix, padded)
        float* W1q = sh + 8704;       // [128 e][64 j]
        float* bm  = sh + 16896;      // [128 e]
        const int r = n >> 3, c = n & 7;
        int ml[4]; int nm = 0;
        if (r > 0) ml[nm++] = n - 8;
        if (r < 7) ml[nm++] = n + 8;
        if (c > 0) ml[nm++] = n - 1;
        if (c < 7) ml[nm++] = n + 1;
        float av[4]; float asum = 0.f;
        for (int d = 0; d < nm; ++d) {
            av[d] = 1.f / (1.f + expf(-adjw[n * NN + ml[d]]));
            asum += av[d];
        }
        const float ainv = 1.f / fmaxf(asum, 1e-6f);
        for (int d = 0; d < nm; ++d) av[d] *= ainv;

        #pragma unroll 4
        for (int i = 0; i < 16; ++i) {              // WmT[e][f]
            int idx = i * 512 + t;
            int f = idx >> 7, e = idx & 127;
            float acc = 0.f;
            for (int d = 0; d < nm; ++d)
                acc = fmaf(av[d], Wemb[(size_t)f * (NN * NE) + ml[d] * NE + e], acc);
            WmT[e * 68 + f] = acc;
        }
        if (t < 128) {
            float accb = 0.f;
            for (int d = 0; d < nm; ++d)
                accb = fmaf(av[d], bemb[ml[d] * NE + t], accb);
            bm[t] = accb;
        }
        #pragma unroll 4
        for (int i = 0; i < 16; ++i) {              // W1q[e][j]
            int idx = i * 512 + t;
            int e = idx >> 6, j6 = idx & 63;
            W1q[e * 64 + j6] = W1[(size_t)e * NH + jq * 64 + j6];
        }
        __syncthreads();

        const int jg = t & 15, fg = t >> 4;         // j-quad, f-pair
        float acc[4][2];
        #pragma unroll
        for (int jj = 0; jj < 4; ++jj) { acc[jj][0] = 0.f; acc[jj][1] = 0.f; }
        float accb[4] = {0.f, 0.f, 0.f, 0.f};
        #pragma unroll 4
        for (int e = 0; e < 128; ++e) {
            float4 w1 = *(const float4*)&W1q[e * 64 + jg * 4];
            float2 wm = *(const float2*)&WmT[e * 68 + fg * 2];
            const float w1v[4] = {w1.x, w1.y, w1.z, w1.w};
            #pragma unroll
            for (int jj = 0; jj < 4; ++jj) {
                acc[jj][0] = fmaf(w1v[jj], wm.x, acc[jj][0]);
                acc[jj][1] = fmaf(w1v[jj], wm.y, acc[jj][1]);
            }
            if (fg == 0) {
                float bb = bm[e];
                #pragma unroll
                for (int jj = 0; jj < 4; ++jj) accb[jj] = fmaf(bb, w1v[jj], accb[jj]);
            }
        }
        // frag-order write: f-pair (e0, e0+1) of chunk (n, jq, mf, kk) lane (hi,lo)
        unsigned short* wf = (unsigned short*)(ws + OFF_WE2F);
        const int mfj = jg >> 2, kk = fg >> 4;
        const int lbase = ((fg >> 2) & 3) * 16, e0 = (fg & 3) * 2;
        const size_t cb = ((((size_t)n * 4 + jq) * 4 + mfj) * 2 + kk) * 64;
        #pragma unroll
        for (int jj = 0; jj < 4; ++jj) {
            int l16 = (jg * 4 + jj) & 15;
            *(unsigned*)(wf + (cb + lbase + l16) * 8 + e0) = bfpack(acc[jj][0], acc[jj][1]);
        }
        if (fg == 0) {
            #pragma unroll
            for (int jj = 0; jj < 4; ++jj) {
                int j = jq * 64 + jg * 4 + jj;
                ws[OFF_BE2 + n * NH + j] = accb[jj] + b1[j];
            }
        }
        return;
    }
    if (bx < 320) {
        // ---- x -> bf16 B-frag order ----
        int g = (bx - 256) * 512 + t;               // 0..32767
        int b = g >> 3, ko = g & 7;
        float4 v0 = ((const float4*)x)[b * 16 + ko * 2];
        float4 v1 = ((const float4*)x)[b * 16 + ko * 2 + 1];
        union { unsigned u[4]; short8 v; } cv;
        cv.u[0] = bfpack(v0.x, v0.y); cv.u[1] = bfpack(v0.z, v0.w);
        cv.u[2] = bfpack(v1.x, v1.y); cv.u[3] = bfpack(v1.z, v1.w);
        int bt = b >> 6, nf = (b >> 4) & 3, kk = ko >> 2, l = (ko & 3) * 16 + (b & 15);
        ((short8*)(ws + OFF_XBF))[(((size_t)bt * 4 + nf) * 2 + kk) * 64 + l] = cv.v;
        return;
    }
    // ---- Wattn blocks: jt = bx-320 handles j = jt*64..+63 ----
    const int jt = bx - 320;
    float* Ks  = sh;            // [6][128]
    float* WqK = sh + 768;      // [128][8] (pad)
    float* W2t = sh + 1792;     // [64][129]
    float* waT = sh + 10048;    // [64][8]
    for (int q = t; q < NA * NE; q += 512) {
        int a = q >> 7, e2 = q & 127;
        float acc = 0.f;
        for (int e = 0; e < NE; ++e) acc = fmaf(basis[a * NE + e], Wk[e * NE + e2], acc);
        Ks[a * NE + e2] = acc;
    }
    __syncthreads();
    for (int q = t; q < NE * NA; q += 512) {
        int e = q / NA, a = q - e * NA;
        float acc = 0.f;
        for (int e2 = 0; e2 < NE; ++e2) acc = fmaf(Wq[e * NE + e2], Ks[a * NE + e2], acc);
        WqK[e * 8 + a] = acc;
    }
    __syncthreads();
    for (int i = 0; i < 16; ++i) {                  // stage W2 rows jt*64..+63
        int idx = i * 512 + t;
        int jr = idx >> 7, e = idx & 127;
        W2t[jr * 129 + e] = W2[(size_t)(jt * 64 + jr) * NE + e];
    }
    __syncthreads();
    const float scale = 1.f / (sqrtf(128.f) + 1e-8f);
    unsigned short* wf16 = (unsigned short*)(ws + OFF_WATTNF);
    if (t < 256) {
        const int jl = t & 63, ag = t >> 6;
        const int j = jt * 64 + jl;
        const int na = (ag < 2) ? 2 : 1;
        for (int ai = 0; ai < na; ++ai) {
            int a = ag + ai * 4;
            float acc = 0.f;
            for (int e = 0; e < NE; ++e)
                acc = fmaf(W2t[jl * 129 + e], WqK[e * 8 + a], acc);
            float v = acc * scale;
            waT[jl * 8 + a] = v;
            wf16[((j >> 3) * 16 + a) * 8 + (j & 7)] = bf16r(v);
        }
        if (ag == 3) wf16[((j >> 3) * 16 + 6) * 8 + (j & 7)] = bf16r(1.0f);  // ones col
        for (int a7 = 7 + ag; a7 < 16; a7 += 4)
            wf16[((j >> 3) * 16 + a7) * 8 + (j & 7)] = 0;
    }
    __syncthreads();
    if (t < 256) {   // 16x16x16 A-frag layout: [jt][mf][l][4 bf16]
        int mf = t >> 6, l = t & 63, lo = l & 15, hi = l >> 4;
        float v[4];
        #pragma unroll
        for (int e = 0; e < 4; ++e) {
            int row = mf * 16 + hi * 4 + e;
            v[e] = (lo < 6) ? waT[row * 8 + lo] : (lo == 6 ? 1.f : 0.f);
        }
        unsigned* dst = (unsigned*)(ws + OFF_WATTN16);
        dst[(((size_t)jt * 4 + mf) * 64 + l) * 2 + 0] = bfpack(v[0], v[1]);
        dst[(((size_t)jt * 4 + mf) * 64 + l) * 2 + 1] = bfpack(v[2], v[3]);
    }
    if (jt == 0) {
        if (t < NA) {
            float acc = 0.f;
            for (int e = 0; e < NE; ++e) acc = fmaf(b2[e], WqK[e * 8 + t], acc);
            ws[OFF_BATTN + t] = acc * scale;
        }
        if (t < 64) ws[OFF_S + t] = 0.f;
    }
}

// ---------------------------------------------------------------- A:
// per (bt,n): GEMM1 (MFMA): hT[j=256][b=64] = We2^T @ x^T, relu+bias;
// GEMM2: 16x16x16 MFMA straight from the D-register layout (no shuffles).
__global__ __launch_bounds__(256) void kA(float* __restrict__ ws) {
    const int bt = blockIdx.x, n = blockIdx.y;
    const int t = threadIdx.x, w = t >> 6, l = t & 63, lo = l & 15, hi = l >> 4;
    const int j0 = w * 64;
    __shared__ float red[4][8][64];

    const short8* Af = (const short8*)(ws + OFF_WE2F);
    const short8* Bf = (const short8*)(ws + OFF_XBF);
    short8 afr[4][2], bfr[4][2];
    #pragma unroll
    for (int mf = 0; mf < 4; ++mf)
        #pragma unroll
        for (int kk = 0; kk < 2; ++kk)
            afr[mf][kk] = Af[(((size_t)n * 4 + w) * 4 + mf) * 2 * 64 + (size_t)kk * 64 + l];
    #pragma unroll
    for (int nf = 0; nf < 4; ++nf)
        #pragma unroll
        for (int kk = 0; kk < 2; ++kk)
            bfr[nf][kk] = Bf[(((size_t)bt * 4 + nf) * 2 + kk) * 64 + l];
#if USE_MFMA16
    const short4v* W16 = (const short4v*)(ws + OFF_WATTN16);
    short4v wfr[4];
    #pragma unroll
    for (int mf = 0; mf < 4; ++mf) wfr[mf] = W16[((size_t)w * 4 + mf) * 64 + l];
#endif
    f32x4 be2r[4];
    #pragma unroll
    for (int mf = 0; mf < 4; ++mf)
        be2r[mf] = *(const f32x4*)(ws + OFF_BE2 + n * NH + j0 + mf * 16 + hi * 4);

    f32x4 zero = {0.f, 0.f, 0.f, 0.f};
    f32x4 acc[4][4];
    #pragma unroll
    for (int mf = 0; mf < 4; ++mf)
        #pragma unroll
        for (int nf = 0; nf < 4; ++nf) acc[mf][nf] = zero;

    #pragma unroll
    for (int kk = 0; kk < 2; ++kk)
        #pragma unroll
        for (int mf = 0; mf < 4; ++mf)
            #pragma unroll
            for (int nf = 0; nf < 4; ++nf)
                acc[mf][nf] = __builtin_amdgcn_mfma_f32_16x16x32_bf16(
                    afr[mf][kk], bfr[nf][kk], acc[mf][nf], 0, 0, 0);

    // h = relu(acc + be2[j]); pack bf16 pairs (j = j0+mf*16+hi*4+i, b = nf*16+lo)
    unsigned P[4][4][2];
    #pragma unroll
    for (int mf = 0; mf < 4; ++mf) {
        #pragma unroll
        for (int nf = 0; nf < 4; ++nf) {
            float h0 = fmaxf(acc[mf][nf][0] + be2r[mf][0], 0.f);
            float h1 = fmaxf(acc[mf][nf][1] + be2r[mf][1], 0.f);
            float h2 = fmaxf(acc[mf][nf][2] + be2r[mf][2], 0.f);
            float h3 = fmaxf(acc[mf][nf][3] + be2r[mf][3], 0.f);
            P[mf][nf][0] = cvtpk(h0, h1);
            P[mf][nf][1] = cvtpk(h2, h3);
        }
    }

    // GEMM2: attnT[a16][b64]; K=16 MFMA consumes D-layout directly
    f32x4 acc2[4];
    #pragma unroll
    for (int nf = 0; nf < 4; ++nf) acc2[nf] = zero;
#if USE_MFMA16
    #pragma unroll
    for (int mf = 0; mf < 4; ++mf)
        #pragma unroll
        for (int nf = 0; nf < 4; ++nf) {
            union { unsigned u[2]; short4v v; } pv;
            pv.u[0] = P[mf][nf][0]; pv.u[1] = P[mf][nf][1];
            acc2[nf] = __builtin_amdgcn_mfma_f32_16x16x16bf16_1k(
                wfr[mf], pv.v, acc2[nf], 0, 0, 0);
        }
#else
    const short8* Wf = (const short8*)(ws + OFF_WATTNF);
    #pragma unroll
    for (int kk2 = 0; kk2 < 2; ++kk2) {
        short8 a2 = Wf[(size_t)(w * 2 + kk2) * 64 + l];
        #pragma unroll
        for (int nf = 0; nf < 4; ++nf) {
            unsigned bq[4];
            #pragma unroll
            for (int q = 0; q < 4; ++q) {
                int s = ((hi & 1) * 2 + (q >> 1)) * 16 + lo;
                unsigned vA = (unsigned)__shfl((int)P[2 * kk2 + 0][nf][q & 1], s, 64);
                unsigned vB = (unsigned)__shfl((int)P[2 * kk2 + 1][nf][q & 1], s, 64);
                bq[q] = (hi >= 2) ? vB : vA;
            }
            union { unsigned u[4]; short8 v; } cv;
            cv.u[0] = bq[0]; cv.u[1] = bq[1]; cv.u[2] = bq[2]; cv.u[3] = bq[3];
            acc2[nf] = __builtin_amdgcn_mfma_f32_16x16x32_bf16(a2, cv.v, acc2[nf], 0, 0, 0);
        }
    }
#endif

    // cross-wave reduce (only a-rows 0..7 matter -> hi<2 lanes)
    if (hi < 2) {
        #pragma unroll
        for (int nf = 0; nf < 4; ++nf)
            #pragma unroll
            for (int i = 0; i < 4; ++i)
                red[w][hi * 4 + i][nf * 16 + lo] = acc2[nf][i];
    }
    __syncthreads();

    const int rb = t & 63, a0 = t >> 6, a1 = a0 + 4;
    float v0 = red[0][a0][rb] + red[1][a0][rb] + red[2][a0][rb] + red[3][a0][rb];
    float v1 = red[0][a1][rb] + red[1][a1][rb] + red[2][a1][rb] + red[3][a1][rb];
    if (a1 == 6) {   // wave 2: ones-column = h row-sums -> global S[n]
        float hs = v1;
        #pragma unroll
        for (int m = 1; m < 64; m <<= 1) hs += __shfl_xor(hs, m, 64);
        if (l == 0) atomicAdd(ws + OFF_S + n, hs);
    }
    __syncthreads();                       // done reading red
    float* red2 = &red[0][0][0];           // [64 b][8 a]
    red2[rb * 8 + a0] = v0;
    red2[rb * 8 + a1] = v1;
    __syncthreads();
    if (t < 128) {                         // ARAW[b][n][8]
        int i = t >> 1, half = t & 1;
        float4 v = *(const float4*)&red2[i * 8 + half * 4];
        *(float4*)(ws + OFF_ARAW + ((size_t)(bt * 64 + i) * 64 + n) * 8 + half * 4) = v;
    }
}

// ---------------------------------------------------------------- C:
// block = one batch row b: thread0 scalar gate chain (c), contiguous 2 KB
// ARAW read via LDS, softmax(6) per token, basis in registers, 32 KB write.
__global__ __launch_bounds__(256) void kC(const float* __restrict__ ws,
                                          const float* __restrict__ basis,
                                          const float* __restrict__ mW1, const float* __restrict__ mb1,
                                          const float* __restrict__ mW2, const float* __restrict__ mb2,
                                          const float* __restrict__ gW1, const float* __restrict__ gb1,
                                          const float* __restrict__ gW2, const float* __restrict__ gb2,
                                          float* __restrict__ out) {
    const int b = blockIdx.x;
    const int t = threadIdx.x;
    __shared__ float ars[512];
    __shared__ float sw[64][8];
    __shared__ float csh;
    if (t < 128)
        ((float4*)ars)[t] = ((const float4*)(ws + OFF_ARAW + (size_t)b * 512))[t];
    const int e0 = (t * 4) & 127;          // invariant across the store loop
    float4 bR[6];
    #pragma unroll
    for (int a = 0; a < 6; ++a) bR[a] = *(const float4*)&basis[a * NE + e0];
    if (t == 0) {   // scalar gate chain
        float S = 0.f;
        for (int i = 0; i < 64; ++i) S += ws[OFF_S + i];
        float s = S / ((float)NB * NN * NH);
        float accm = mb2[0];
        for (int i = 0; i < 8; ++i) accm += fmaxf(s * mW1[i] + mb1[i], 0.f) * mW2[i];
        float m = 1.f / (1.f + expf(-accm));
        float state = 0.9f * 0.5f + 0.1f * m;
        float c1 = 1.f + 0.1f * (state - 0.5f);
        float sg = c1 * s;
        float accg = gb2[0];
        for (int i = 0; i < 16; ++i) accg += fmaxf(sg * gW1[i] + gb1[i], 0.f) * gW2[i];
        float g = 1.f / (1.f + expf(-accg));
        csh = c1 * g;
    }
    __syncthreads();
    if (t < 64) {
        const float c = csh;
        float at[6], mx = -1e30f;
        #pragma unroll
        for (int a = 0; a < 6; ++a) {
            at[a] = fmaf(c, ars[t * 8 + a], ws[OFF_BATTN + a]);
            mx = fmaxf(mx, at[a]);
        }
        float ex[6], ssum = 0.f;
        #pragma unroll
        for (int a = 0; a < 6; ++a) { ex[a] = expf(at[a] - mx); ssum += ex[a]; }
        float inv = 1.f / ssum;
        #pragma unroll
        for (int a = 0; a < 6; ++a) sw[t][a] = ex[a] * inv;
    }
    __syncthreads();
    float* op = out + (size_t)b * (NN * NE);
    #pragma unroll
    for (int i = 0; i < 8; ++i) {
        int idx = i * 1024 + t * 4;          // e = idx&127 == e0 for all i
        int nn = idx >> 7;
        float wv[6];
        #pragma unroll
        for (int a = 0; a < 6; ++a) wv[a] = sw[nn][a];
        float4 r;
        #pragma unroll
        for (int cc = 0; cc < 4; ++cc) {
            float o = 0.f;
            #pragma unroll
            for (int a = 0; a < 6; ++a) o = fmaf(wv[a], ((const float*)&bR[a])[cc], o);
            ((float*)&r)[cc] = fminf(fmaxf(o, -3.f), 3.f);
        }
        *(float4*)(op + idx) = r;
    }
}

extern "C" void kernel_launch(void* const* d_in, const int* in_sizes, int n_in,
                              void* d_out, int out_size, void* d_ws, size_t ws_size,
                              hipStream_t stream) {
    const float* x     = (const float*)d_in[0];
    const float* Wemb  = (const float*)d_in[1];
    const float* bemb  = (const float*)d_in[2];
    const float* adjw  = (const float*)d_in[3];
    const float* W1    = (const float*)d_in[4];
    const float* b1    = (const float*)d_in[5];
    const float* W2    = (const float*)d_in[6];
    const float* b2    = (const float*)d_in[7];
    const float* basis = (const float*)d_in[8];
    const float* Wq    = (const float*)d_in[9];
    const float* Wk    = (const float*)d_in[10];
    const float* mW1   = (const float*)d_in[11];
    const float* mb1   = (const float*)d_in[12];
    const float* mW2   = (const float*)d_in[13];
    const float* mb2   = (const float*)d_in[14];
    const float* gW1   = (const float*)d_in[15];
    const float* gb1   = (const float*)d_in[16];
    const float* gW2   = (const float*)d_in[17];
    const float* gb2   = (const float*)d_in[18];
    float* ws  = (float*)d_ws;
    float* out = (float*)d_out;

    kP<<<324, 512, 0, stream>>>(x, Wemb, bemb, adjw, W1, b1, basis, Wq, Wk, W2, b2, ws);
    kA<<<dim3(64, 64), 256, 0, stream>>>(ws);
    kC<<<NB, 256, 0, stream>>>(ws, basis, mW1, mb1, mW2, mb2, gW1, gb1, gW2, gb2, out);
}